// Round 2
// baseline (168.131 us; speedup 1.0000x reference)
//
#include <hip/hip_runtime.h>

#define NB 4
#define NN 2048
#define NF 256
#define NK 4
#define ND 64
#define NEG 0.2f

typedef _Float16 f16;
typedef _Float16 f16x4 __attribute__((ext_vector_type(4)));
typedef float f32x4 __attribute__((ext_vector_type(4)));

// ---------------------------------------------------------------------------
// K1: Wh^T = (x @ W)^T per (b,k), stored f16 as wht[b][k][d][n]; also
// s[b,k,n] = Wh·a_src, t[b,k,n] = Wh·a_dst in f32 (from the f32 accumulators).
// ---------------------------------------------------------------------------
__global__ __launch_bounds__(256) void k1_gemm(
    const float* __restrict__ x,      // (B,N,F)
    const float* __restrict__ Wm,     // (K,F,D)
    const float* __restrict__ a_src,  // (K,D)
    const float* __restrict__ a_dst,  // (K,D)
    f16* __restrict__ wht,            // (B,K,D,N)
    float* __restrict__ sbuf,         // (B,K,N)
    float* __restrict__ tbuf)         // (B,K,N)
{
    const int gx  = blockIdx.x;   // n-group of 128
    const int k   = blockIdx.y;
    const int b   = blockIdx.z;
    const int tid = threadIdx.x;
    const int wv  = tid >> 6;
    const int l   = tid & 63;
    const int q   = l >> 4;
    const int r16 = l & 15;

    __shared__ f16 wt[64 * 256];  // W^T: wt[d][f], xor-swizzled in f

    for (int fc = 0; fc < 64; ++fc) {
        int f = fc * 4 + wv;
        int d = l;
        wt[d * 256 + (f ^ ((d & 7) << 3))] = (f16)Wm[(k * NF + f) * ND + d];
    }
    __syncthreads();

    const int ncol0 = gx * 128 + wv * 32;
    f32x4 acc[2][4];
#pragma unroll
    for (int nt = 0; nt < 2; ++nt)
#pragma unroll
        for (int dt = 0; dt < 4; ++dt)
            acc[nt][dt] = (f32x4){0.f, 0.f, 0.f, 0.f};

    for (int fs = 0; fs < 16; ++fs) {           // K-steps of 16
        const int f0 = fs * 16 + q * 4;          // this lane's 4 k-elems
        f16x4 af[4];
#pragma unroll
        for (int dt = 0; dt < 4; ++dt) {
            int d = dt * 16 + r16;               // A row
            af[dt] = *(const f16x4*)&wt[d * 256 + (f0 ^ ((d & 7) << 3))];
        }
#pragma unroll
        for (int nt = 0; nt < 2; ++nt) {
            int n = ncol0 + nt * 16 + r16;       // B col
            float4 xv = *(const float4*)&x[((size_t)(b * NN + n)) * NF + f0];
            f16x4 bf = {(f16)xv.x, (f16)xv.y, (f16)xv.z, (f16)xv.w};
#pragma unroll
            for (int dt = 0; dt < 4; ++dt)
                acc[nt][dt] = __builtin_amdgcn_mfma_f32_16x16x16f16(
                    af[dt], bf, acc[nt][dt], 0, 0, 0);
        }
    }

    float asv[4][4], adv[4][4];
#pragma unroll
    for (int dt = 0; dt < 4; ++dt)
#pragma unroll
        for (int rr = 0; rr < 4; ++rr) {
            int d = dt * 16 + q * 4 + rr;
            asv[dt][rr] = a_src[k * ND + d];
            adv[dt][rr] = a_dst[k * ND + d];
        }

#pragma unroll
    for (int nt = 0; nt < 2; ++nt) {
        int n = ncol0 + nt * 16 + r16;
        float sp = 0.f, tp = 0.f;
#pragma unroll
        for (int dt = 0; dt < 4; ++dt)
#pragma unroll
            for (int rr = 0; rr < 4; ++rr) {
                float v = acc[nt][dt][rr];
                int d = dt * 16 + q * 4 + rr;    // C row = d'
                wht[((size_t)(b * NK + k) * ND + d) * NN + n] = (f16)v;
                sp += v * asv[dt][rr];
                tp += v * adv[dt][rr];
            }
        sp += __shfl_xor(sp, 16);
        sp += __shfl_xor(sp, 32);
        tp += __shfl_xor(tp, 16);
        tp += __shfl_xor(tp, 32);
        if (q == 0) {
            sbuf[(b * NK + k) * NN + n] = sp;
            tbuf[(b * NK + k) * NN + n] = tp;
        }
    }
}

// ---------------------------------------------------------------------------
// K2 v2: fused masked-softmax attention, j-split for occupancy.
// Block = 1024 thr = 16 waves = 4 heads x 4 j-chunks of 512. Each wave
// accumulates a partial (acc, denom) over its chunk; LDS combine at the end.
// Rank-1 scores: e=lrelu(s_i+t_j); shift-invariant softmax, shift=lrelu(s_i);
// lrelu(e)-shift computed as max(u, fma(0.2,u,-0.8*shift)) with u=s+t-shift.
// Mask folded as multiply by (float)adj (adj in {0,1}); self-loop diagonal
// fixed in the single 32-wide j-tile per block that contains it.
// ---------------------------------------------------------------------------
__global__ __launch_bounds__(1024, 8) void k2_attn(
    const int* __restrict__ adj,     // (B,N,N)
    const f16* __restrict__ wht,     // (B,K,D,N)
    const float* __restrict__ sbuf,  // (B,K,N)
    const float* __restrict__ tbuf,  // (B,K,N)
    float* __restrict__ out)         // (B,N,K*D)
{
    const int i0  = blockIdx.x * 16;
    const int b   = blockIdx.y;
    const int tid = threadIdx.x;
    const int w   = tid >> 6;        // wave id 0..15
    const int k   = w >> 2;          // head
    const int c   = w & 3;           // j-chunk
    const int l   = tid & 63;
    const int q   = l >> 4;
    const int r16 = l & 15;
    const int iglob = i0 + r16;

    __shared__ float lacc[16 * 1024];   // per-wave C fragments (f32)
    __shared__ float lden[16 * 16];     // per-wave row denominators

    const float s_lane = sbuf[(b * NK + k) * NN + iglob];
    const float shift  = fmaxf(s_lane, 0.f) + NEG * fminf(s_lane, 0.f);
    const float sp     = s_lane - shift;       // u = sp + t
    const float c2     = -0.8f * shift;        // v = fma(0.2, u, c2)
    const float* __restrict__ trow = tbuf + (b * NK + k) * NN;
    const int*   __restrict__ arow = adj + ((size_t)(b * NN) + iglob) * NN;
    const f16*   __restrict__ whb  = wht + (size_t)(b * NK + k) * ND * NN;

    // the one 32-wide j-tile containing this block's diagonal entries
    const int jdiag = ((i0 >> 9) == c) ? (i0 & ~31) : -1;

    float denom = 0.f;
    f32x4 acc[4];
#pragma unroll
    for (int dt = 0; dt < 4; ++dt) acc[dt] = (f32x4){0.f, 0.f, 0.f, 0.f};

    const int jbase = c * 512;
    for (int jt = 0; jt < 16; ++jt) {
        const int j0 = jbase + jt * 32;
        const int ja = j0 + q * 4;       // first K=16 half
        const int jb = ja + 16;          // second half
        float4 t0 = *(const float4*)(trow + ja);
        float4 t1 = *(const float4*)(trow + jb);
        int4  a0  = *(const int4*)(arow + ja);
        int4  a1  = *(const int4*)(arow + jb);
        float tv0[4] = {t0.x, t0.y, t0.z, t0.w};
        float tv1[4] = {t1.x, t1.y, t1.z, t1.w};
        float m0[4]  = {(float)a0.x, (float)a0.y, (float)a0.z, (float)a0.w};
        float m1[4]  = {(float)a1.x, (float)a1.y, (float)a1.z, (float)a1.w};
        if (j0 == jdiag) {               // wave-uniform, 1 of 16 iterations
#pragma unroll
            for (int e = 0; e < 4; ++e) {
                if (ja + e == iglob) m0[e] = 1.f;
                if (jb + e == iglob) m1[e] = 1.f;
            }
        }
        float w0[4], w1[4];
#pragma unroll
        for (int e = 0; e < 4; ++e) {
            float u0 = sp + tv0[e];
            float g0 = fmaxf(u0, __builtin_fmaf(NEG, u0, c2));
            w0[e] = __expf(g0) * m0[e];
            float u1 = sp + tv1[e];
            float g1 = fmaxf(u1, __builtin_fmaf(NEG, u1, c2));
            w1[e] = __expf(g1) * m1[e];
            denom += w0[e] + w1[e];
        }
        f16x4 pa0 = {(f16)w0[0], (f16)w0[1], (f16)w0[2], (f16)w0[3]};
        f16x4 pa1 = {(f16)w1[0], (f16)w1[1], (f16)w1[2], (f16)w1[3]};
#pragma unroll
        for (int dt = 0; dt < 4; ++dt) {
            const f16* wrow = whb + (size_t)(dt * 16 + r16) * NN;
            f16x4 bf0 = *(const f16x4*)(wrow + ja);
            f16x4 bf1 = *(const f16x4*)(wrow + jb);
            acc[dt] = __builtin_amdgcn_mfma_f32_16x16x16f16(pa0, bf0, acc[dt], 0, 0, 0);
            acc[dt] = __builtin_amdgcn_mfma_f32_16x16x16f16(pa1, bf1, acc[dt], 0, 0, 0);
        }
    }

    // stash partials: lane l's f32x4 per dt at [w][dt][l] (conflict-free b128)
#pragma unroll
    for (int dt = 0; dt < 4; ++dt)
        *(f32x4*)&lacc[w * 1024 + dt * 256 + l * 4] = acc[dt];

    denom += __shfl_xor(denom, 16);
    denom += __shfl_xor(denom, 32);
    if (l < 16) lden[w * 16 + l] = denom;
    __syncthreads();

    // combine: wave w owns output row r=w; lane = (head kk, col c16)
    {
        const int r = w, rr = r & 3, qrow = r >> 2;
        const int kk = l >> 4, c16 = l & 15;
        float den = 0.f;
#pragma unroll
        for (int cc = 0; cc < 4; ++cc) den += lden[(kk * 4 + cc) * 16 + r];
        const float inv = 1.f / (den + 1e-10f);
#pragma unroll
        for (int dt = 0; dt < 4; ++dt) {
            float sum = 0.f;
#pragma unroll
            for (int cc = 0; cc < 4; ++cc)
                sum += lacc[(kk * 4 + cc) * 1024 + dt * 256 + qrow * 64 + c16 * 4 + rr];
            out[((size_t)(b * NN) + i0 + r) * (NK * ND) + kk * 64 + dt * 16 + c16] =
                sum * inv;
        }
    }
}

extern "C" void kernel_launch(void* const* d_in, const int* in_sizes, int n_in,
                              void* d_out, int out_size, void* d_ws, size_t ws_size,
                              hipStream_t stream) {
    const float* x     = (const float*)d_in[0];
    const int*   adj   = (const int*)d_in[1];
    const float* Wm    = (const float*)d_in[2];
    const float* a_src = (const float*)d_in[3];
    const float* a_dst = (const float*)d_in[4];
    float* out = (float*)d_out;

    char* ws = (char*)d_ws;
    f16*   wht  = (f16*)ws;                                   // 4 MiB
    float* sbuf = (float*)(ws + (4u << 20));                  // 128 KiB
    float* tbuf = (float*)(ws + (4u << 20) + NB * NK * NN * sizeof(float));

    k1_gemm<<<dim3(16, NK, NB), 256, 0, stream>>>(x, Wm, a_src, a_dst, wht, sbuf, tbuf);
    k2_attn<<<dim3(NN / 16, NB), 1024, 0, stream>>>(adj, wht, sbuf, tbuf, out);
}

// Round 3
// 72.834 us; speedup vs baseline: 2.3084x; 2.3084x over previous
//
#include <hip/hip_runtime.h>

#define NB 4
#define NN 2048
#define NF 256
#define NK 4
#define ND 64
#define NEG 0.2f

typedef _Float16 f16;
typedef _Float16 f16x4 __attribute__((ext_vector_type(4)));
typedef float f32x4 __attribute__((ext_vector_type(4)));

__device__ __forceinline__ int swz3(int d) { return (d ^ (d >> 3)) & 7; }

// ---------------------------------------------------------------------------
// K1: Wh^T = (x @ W)^T per (b,k). Output layout: TILE-MAJOR + SWIZZLED:
//   wht[((b*NK+k)*64 + jt)*2048 + d*32 + ((j&31) ^ (swz3(d)<<2))]
// i.e. each 32-j tile is a contiguous 4KB block of [d][32] f16 with an XOR
// swizzle on the 8B slot index, so K2 can global_load_lds it LINEARLY and
// ds_read_b64 fragments conflict-free. Also s = Wh a_src, t = Wh a_dst (f32).
// ---------------------------------------------------------------------------
__global__ __launch_bounds__(256) void k1_gemm(
    const float* __restrict__ x,      // (B,N,F)
    const float* __restrict__ Wm,     // (K,F,D)
    const float* __restrict__ a_src,  // (K,D)
    const float* __restrict__ a_dst,  // (K,D)
    f16* __restrict__ wht,            // tile-major, see above
    float* __restrict__ sbuf,         // (B,K,N)
    float* __restrict__ tbuf)         // (B,K,N)
{
    const int gx  = blockIdx.x;   // n-group of 128
    const int k   = blockIdx.y;
    const int b   = blockIdx.z;
    const int tid = threadIdx.x;
    const int wv  = tid >> 6;
    const int l   = tid & 63;
    const int q   = l >> 4;
    const int r16 = l & 15;

    __shared__ f16 wt[64 * 256];  // W^T: wt[d][f], xor-swizzled in f

    for (int fc = 0; fc < 64; ++fc) {
        int f = fc * 4 + wv;
        int d = l;
        wt[d * 256 + (f ^ ((d & 7) << 3))] = (f16)Wm[(k * NF + f) * ND + d];
    }
    __syncthreads();

    const int ncol0 = gx * 128 + wv * 32;
    f32x4 acc[2][4];
#pragma unroll
    for (int nt = 0; nt < 2; ++nt)
#pragma unroll
        for (int dt = 0; dt < 4; ++dt)
            acc[nt][dt] = (f32x4){0.f, 0.f, 0.f, 0.f};

    for (int fs = 0; fs < 16; ++fs) {           // K-steps of 16
        const int f0 = fs * 16 + q * 4;          // this lane's 4 k-elems
        f16x4 af[4];
#pragma unroll
        for (int dt = 0; dt < 4; ++dt) {
            int d = dt * 16 + r16;               // A row
            af[dt] = *(const f16x4*)&wt[d * 256 + (f0 ^ ((d & 7) << 3))];
        }
#pragma unroll
        for (int nt = 0; nt < 2; ++nt) {
            int n = ncol0 + nt * 16 + r16;       // B col
            float4 xv = *(const float4*)&x[((size_t)(b * NN + n)) * NF + f0];
            f16x4 bf = {(f16)xv.x, (f16)xv.y, (f16)xv.z, (f16)xv.w};
#pragma unroll
            for (int dt = 0; dt < 4; ++dt)
                acc[nt][dt] = __builtin_amdgcn_mfma_f32_16x16x16f16(
                    af[dt], bf, acc[nt][dt], 0, 0, 0);
        }
    }

    float asv[4][4], adv[4][4];
#pragma unroll
    for (int dt = 0; dt < 4; ++dt)
#pragma unroll
        for (int rr = 0; rr < 4; ++rr) {
            int d = dt * 16 + q * 4 + rr;
            asv[dt][rr] = a_src[k * ND + d];
            adv[dt][rr] = a_dst[k * ND + d];
        }

    const int jt = gx * 4 + wv;  // this wave's 32-col tile index
    f16* __restrict__ tile = wht + ((size_t)(b * NK + k) * 64 + jt) * 2048;

#pragma unroll
    for (int nt = 0; nt < 2; ++nt) {
        int n  = ncol0 + nt * 16 + r16;
        int j5 = nt * 16 + r16;               // n & 31
        float sp = 0.f, tp = 0.f;
#pragma unroll
        for (int dt = 0; dt < 4; ++dt)
#pragma unroll
            for (int rr = 0; rr < 4; ++rr) {
                float v = acc[nt][dt][rr];
                int d = dt * 16 + q * 4 + rr;    // C row = d'
                tile[d * 32 + (j5 ^ (swz3(d) << 2))] = (f16)v;
                sp += v * asv[dt][rr];
                tp += v * adv[dt][rr];
            }
        sp += __shfl_xor(sp, 16);
        sp += __shfl_xor(sp, 32);
        tp += __shfl_xor(tp, 16);
        tp += __shfl_xor(tp, 32);
        if (q == 0) {
            sbuf[(b * NK + k) * NN + n] = sp;
            tbuf[(b * NK + k) * NN + n] = tp;
        }
    }
}

// ---------------------------------------------------------------------------
// K2 v3: fused masked-softmax attention, LDS-staged Wh.
// Block = 512 thr = 8 waves, ONE head (blockIdx.y), 128 i-rows (16/wave),
// full j-walk in 32 steps of 64 j. Per step: one global_load_lds_dwordx4 per
// thread stages 8KB (two pre-swizzled 4KB tiles) into a double buffer;
// adj/t are register-double-buffered. Schedule per step: barrier (drain
// stage issued last iter) -> issue next stage+loads -> compute (ds_read
// conflict-free + exp + MFMA). No cross-wave combine: each wave owns rows.
// ---------------------------------------------------------------------------
__global__ __launch_bounds__(512) void k2_attn(
    const int* __restrict__ adj,     // (B,N,N)
    const f16* __restrict__ wht,     // tile-major swizzled
    const float* __restrict__ sbuf,  // (B,K,N)
    const float* __restrict__ tbuf,  // (B,K,N)
    float* __restrict__ out)         // (B,N,K*D)
{
    const int i0  = blockIdx.x * 128;
    const int k   = blockIdx.y;
    const int b   = blockIdx.z;
    const int tid = threadIdx.x;
    const int w   = tid >> 6;
    const int l   = tid & 63;
    const int q   = l >> 4;
    const int r16 = l & 15;
    const int iglob = i0 + w * 16 + r16;

    __shared__ f16 sh[2][4096];          // 2 x 8KB (two 4KB tiles each)
    char* shb = (char*)&sh[0][0];

    const float s_lane = sbuf[(b * NK + k) * NN + iglob];
    const float shift  = fmaxf(s_lane, 0.f) + NEG * fminf(s_lane, 0.f);
    const float sp     = s_lane - shift;
    const float c2     = -0.8f * shift;
    const float* __restrict__ trow = tbuf + (b * NK + k) * NN;
    const int*   __restrict__ arow = adj + ((size_t)(b * NN) + iglob) * NN;
    const char*  gtiles = (const char*)wht + (size_t)(b * NK + k) * 262144;

    const int jdtile = (i0 + w * 16) >> 5;   // 32-j tile holding the diagonal

    float denom = 0.f;
    f32x4 acc[4];
#pragma unroll
    for (int dt = 0; dt < 4; ++dt) acc[dt] = (f32x4){0.f, 0.f, 0.f, 0.f};

#define STAGE(bb, ss)                                                          \
    __builtin_amdgcn_global_load_lds(                                          \
        (const __attribute__((address_space(1))) void*)(gtiles +               \
            (size_t)(ss) * 8192 + tid * 16),                                   \
        (__attribute__((address_space(3))) void*)(shb + (bb) * 8192 + w * 1024),\
        16, 0, 0)

#define LOADRT(ss, A0, A1, T0, T1)                                             \
    do {                                                                       \
        _Pragma("unroll") for (int h = 0; h < 2; ++h) {                        \
            int ja = (ss) * 64 + h * 32 + q * 4;                               \
            T0[h] = *(const float4*)(trow + ja);                               \
            T1[h] = *(const float4*)(trow + ja + 16);                          \
            A0[h] = *(const int4*)(arow + ja);                                 \
            A1[h] = *(const int4*)(arow + ja + 16);                            \
        }                                                                      \
    } while (0)

#define COMPUTE(ss, bb, A0, A1, T0, T1)                                        \
    do {                                                                       \
        _Pragma("unroll") for (int h = 0; h < 2; ++h) {                        \
            const int j0 = (ss) * 64 + h * 32;                                 \
            const int ja = j0 + q * 4, jb = ja + 16;                           \
            float tv0[4] = {T0[h].x, T0[h].y, T0[h].z, T0[h].w};               \
            float tv1[4] = {T1[h].x, T1[h].y, T1[h].z, T1[h].w};               \
            float m0[4] = {(float)A0[h].x, (float)A0[h].y,                     \
                           (float)A0[h].z, (float)A0[h].w};                    \
            float m1[4] = {(float)A1[h].x, (float)A1[h].y,                     \
                           (float)A1[h].z, (float)A1[h].w};                    \
            if ((j0 >> 5) == jdtile) {                                         \
                _Pragma("unroll") for (int e = 0; e < 4; ++e) {                \
                    if (ja + e == iglob) m0[e] = 1.f;                          \
                    if (jb + e == iglob) m1[e] = 1.f;                          \
                }                                                              \
            }                                                                  \
            float w0[4], w1[4];                                                \
            _Pragma("unroll") for (int e = 0; e < 4; ++e) {                    \
                float u0 = sp + tv0[e];                                        \
                float g0 = fmaxf(u0, __builtin_fmaf(NEG, u0, c2));             \
                w0[e] = __expf(g0) * m0[e];                                    \
                float u1 = sp + tv1[e];                                        \
                float g1 = fmaxf(u1, __builtin_fmaf(NEG, u1, c2));             \
                w1[e] = __expf(g1) * m1[e];                                    \
                denom += w0[e] + w1[e];                                        \
            }                                                                  \
            f16x4 pa0 = {(f16)w0[0], (f16)w0[1], (f16)w0[2], (f16)w0[3]};      \
            f16x4 pa1 = {(f16)w1[0], (f16)w1[1], (f16)w1[2], (f16)w1[3]};      \
            const char* lb = shb + (bb) * 8192 + h * 4096;                     \
            _Pragma("unroll") for (int dt = 0; dt < 4; ++dt) {                 \
                int d = dt * 16 + r16;                                         \
                int sz = swz3(d);                                              \
                f16x4 bf0 = *(const f16x4*)(lb + d * 64 + ((q ^ sz) << 3));    \
                f16x4 bf1 = *(const f16x4*)(lb + d * 64 + (((q + 4) ^ sz) << 3)); \
                acc[dt] = __builtin_amdgcn_mfma_f32_16x16x16f16(pa0, bf0,      \
                                                                acc[dt], 0, 0, 0); \
                acc[dt] = __builtin_amdgcn_mfma_f32_16x16x16f16(pa1, bf1,      \
                                                                acc[dt], 0, 0, 0); \
            }                                                                  \
        }                                                                      \
    } while (0)

    int4   A0a[2], A1a[2], A0b[2], A1b[2];
    float4 T0a[2], T1a[2], T0b[2], T1b[2];

    STAGE(0, 0);
    LOADRT(0, A0a, A1a, T0a, T1a);

    for (int s2 = 0; s2 < 16; ++s2) {
        const int s = s2 * 2;
        __syncthreads();                       // stage(s)->buf0 landed
        STAGE(1, s + 1);
        LOADRT(s + 1, A0b, A1b, T0b, T1b);
        COMPUTE(s, 0, A0a, A1a, T0a, T1a);     // overlaps stage(s+1)
        __syncthreads();                       // stage(s+1)->buf1 landed
        if (s2 < 15) {
            STAGE(0, s + 2);
            LOADRT(s + 2, A0a, A1a, T0a, T1a);
        }
        COMPUTE(s + 1, 1, A0b, A1b, T0b, T1b); // overlaps stage(s+2)
    }

    // row denominators: each lane ends with full denom of row r16
    denom += __shfl_xor(denom, 16);
    denom += __shfl_xor(denom, 32);

#pragma unroll
    for (int rr = 0; rr < 4; ++rr) {
        int irow = q * 4 + rr;                       // C row
        float dd  = __shfl(denom, (l & 48) | irow);  // lane with r16 == irow
        float inv = 1.f / (dd + 1e-10f);
#pragma unroll
        for (int dt = 0; dt < 4; ++dt)
            out[((size_t)(b * NN) + i0 + w * 16 + irow) * (NK * ND) +
                k * ND + dt * 16 + r16] = acc[dt][rr] * inv;
    }
#undef STAGE
#undef LOADRT
#undef COMPUTE
}

extern "C" void kernel_launch(void* const* d_in, const int* in_sizes, int n_in,
                              void* d_out, int out_size, void* d_ws, size_t ws_size,
                              hipStream_t stream) {
    const float* x     = (const float*)d_in[0];
    const int*   adj   = (const int*)d_in[1];
    const float* Wm    = (const float*)d_in[2];
    const float* a_src = (const float*)d_in[3];
    const float* a_dst = (const float*)d_in[4];
    float* out = (float*)d_out;

    char* ws = (char*)d_ws;
    f16*   wht  = (f16*)ws;                                   // 4 MiB
    float* sbuf = (float*)(ws + (4u << 20));                  // 128 KiB
    float* tbuf = (float*)(ws + (4u << 20) + NB * NK * NN * sizeof(float));

    k1_gemm<<<dim3(16, NK, NB), 256, 0, stream>>>(x, Wm, a_src, a_dst, wht, sbuf, tbuf);
    k2_attn<<<dim3(NN / 128, NK, NB), 512, 0, stream>>>(adj, wht, sbuf, tbuf, out);
}

// Round 4
// 67.008 us; speedup vs baseline: 2.5091x; 1.0869x over previous
//
#include <hip/hip_runtime.h>

#define NB 4
#define NN 2048
#define NF 256
#define NK 4
#define ND 64
#define NEG 0.2f
#define LOG2E 1.4426950408889634f

typedef _Float16 f16;
typedef _Float16 f16x4 __attribute__((ext_vector_type(4)));
typedef _Float16 f16x8 __attribute__((ext_vector_type(8)));
typedef float f32x4 __attribute__((ext_vector_type(4)));

// 2-bit slot swizzle for the wht tile layout (must match k1 store / k2 read)
__device__ __forceinline__ int sz2(int d) { return ((d >> 1) ^ (d >> 3)) & 3; }

// ---------------------------------------------------------------------------
// K0: bit-pack (adj > 0) | I into abit[b][i][jw], jw = j/32 (64 words/row).
// One wave per row; lane l covers j = c*64+l; __ballot -> 64 bits -> lanes
// 0..31 keep word pairs and store 256B/row coalesced. Self-loop bit OR'd in.
// ---------------------------------------------------------------------------
__global__ __launch_bounds__(256) void k0_pack(
    const int* __restrict__ adj, unsigned int* __restrict__ abit)
{
    const int row = blockIdx.x * 4 + (threadIdx.x >> 6);  // b*NN + i
    const int l   = threadIdx.x & 63;
    const int i   = row & (NN - 1);
    const int* __restrict__ ar = adj + (size_t)row * NN;

    int v[32];
#pragma unroll
    for (int c = 0; c < 32; ++c) v[c] = ar[c * 64 + l];

    unsigned int kx = 0, ky = 0;
#pragma unroll
    for (int c = 0; c < 32; ++c) {
        unsigned long long m = __ballot(v[c] > 0);
        if (l == c) { kx = (unsigned int)m; ky = (unsigned int)(m >> 32); }
    }
    // self-loop: word jw=i>>5 lives at lane i>>6, component (i>>5)&1
    if (l == (i >> 6)) {
        unsigned int sb = 1u << (i & 31);
        if (((i >> 5) & 1) == 0) kx |= sb; else ky |= sb;
    }
    if (l < 32) {
        uint2 kk; kk.x = kx; kk.y = ky;
        *(uint2*)&abit[(size_t)row * 64 + l * 2] = kk;
    }
}

// ---------------------------------------------------------------------------
// K1: Wh^T = (x @ W)^T per (b,k), f16, tile-major + pair-packed + swizzled:
// tile jt (32 j, 4KB) at wht + ((b*NK+k)*64 + jt)*2048 elems; within tile:
//   elem(d, j5) at d*32 + ((qj ^ sz2(d))<<3) + hi*4 + e,
//   qj=(j5>>2)&3, hi=j5>>4, e=j5&3
// so K2's lane (q,r16) reads its TWO B-fragments as ONE ds_read_b128.
// Also s = Wh a_src, t = Wh a_dst (f32).
// ---------------------------------------------------------------------------
__global__ __launch_bounds__(256) void k1_gemm(
    const float* __restrict__ x,      // (B,N,F)
    const float* __restrict__ Wm,     // (K,F,D)
    const float* __restrict__ a_src,  // (K,D)
    const float* __restrict__ a_dst,  // (K,D)
    f16* __restrict__ wht,            // tile-major, see above
    float* __restrict__ sbuf,         // (B,K,N)
    float* __restrict__ tbuf)         // (B,K,N)
{
    const int gx  = blockIdx.x;   // n-group of 128
    const int k   = blockIdx.y;
    const int b   = blockIdx.z;
    const int tid = threadIdx.x;
    const int wv  = tid >> 6;
    const int l   = tid & 63;
    const int q   = l >> 4;
    const int r16 = l & 15;

    __shared__ f16 wt[64 * 256];  // W^T: wt[d][f], xor-swizzled in f

    for (int fc = 0; fc < 64; ++fc) {
        int f = fc * 4 + wv;
        int d = l;
        wt[d * 256 + (f ^ ((d & 7) << 3))] = (f16)Wm[(k * NF + f) * ND + d];
    }
    __syncthreads();

    const int ncol0 = gx * 128 + wv * 32;
    f32x4 acc[2][4];
#pragma unroll
    for (int nt = 0; nt < 2; ++nt)
#pragma unroll
        for (int dt = 0; dt < 4; ++dt)
            acc[nt][dt] = (f32x4){0.f, 0.f, 0.f, 0.f};

    for (int fs = 0; fs < 16; ++fs) {           // K-steps of 16
        const int f0 = fs * 16 + q * 4;
        f16x4 af[4];
#pragma unroll
        for (int dt = 0; dt < 4; ++dt) {
            int d = dt * 16 + r16;
            af[dt] = *(const f16x4*)&wt[d * 256 + (f0 ^ ((d & 7) << 3))];
        }
#pragma unroll
        for (int nt = 0; nt < 2; ++nt) {
            int n = ncol0 + nt * 16 + r16;
            float4 xv = *(const float4*)&x[((size_t)(b * NN + n)) * NF + f0];
            f16x4 bf = {(f16)xv.x, (f16)xv.y, (f16)xv.z, (f16)xv.w};
#pragma unroll
            for (int dt = 0; dt < 4; ++dt)
                acc[nt][dt] = __builtin_amdgcn_mfma_f32_16x16x16f16(
                    af[dt], bf, acc[nt][dt], 0, 0, 0);
        }
    }

    float asv[4][4], adv[4][4];
#pragma unroll
    for (int dt = 0; dt < 4; ++dt)
#pragma unroll
        for (int rr = 0; rr < 4; ++rr) {
            int d = dt * 16 + q * 4 + rr;
            asv[dt][rr] = a_src[k * ND + d];
            adv[dt][rr] = a_dst[k * ND + d];
        }

    const int jt = gx * 4 + wv;  // this wave's 32-col tile index
    f16* __restrict__ tile = wht + ((size_t)(b * NK + k) * 64 + jt) * 2048;
    const int qj = r16 >> 2, ee = r16 & 3;

#pragma unroll
    for (int nt = 0; nt < 2; ++nt) {
        int n = ncol0 + nt * 16 + r16;
        float sp = 0.f, tp = 0.f;
#pragma unroll
        for (int dt = 0; dt < 4; ++dt)
#pragma unroll
            for (int rr = 0; rr < 4; ++rr) {
                float v = acc[nt][dt][rr];
                int d = dt * 16 + q * 4 + rr;    // C row = d'
                tile[d * 32 + ((qj ^ sz2(d)) << 3) + nt * 4 + ee] = (f16)v;
                sp += v * asv[dt][rr];
                tp += v * adv[dt][rr];
            }
        sp += __shfl_xor(sp, 16);
        sp += __shfl_xor(sp, 32);
        tp += __shfl_xor(tp, 16);
        tp += __shfl_xor(tp, 32);
        if (q == 0) {
            sbuf[(b * NK + k) * NN + n] = sp;
            tbuf[(b * NK + k) * NN + n] = tp;
        }
    }
}

// ---------------------------------------------------------------------------
// K2 v4: fused masked-softmax attention.
// Block = 512 thr = 8 waves, one (b,k) head, 128 i-rows (16/wave), 16 iters
// of 128 j. Per iter: ONE 16KB global_load_lds stage (double-buffered, one
// barrier), adj mask = one uint4 of bits (from abit, L2-resident), t*log2e
// read from an LDS copy staged once. exp2-domain scoring; B-fragments as
// single swizzled ds_read_b128.
// ---------------------------------------------------------------------------
__global__ __launch_bounds__(512) void k2_attn(
    const unsigned int* __restrict__ abit,  // (B,N,64) bit-mask
    const f16* __restrict__ wht,            // tile-major pair-packed
    const float* __restrict__ sbuf,         // (B,K,N)
    const float* __restrict__ tbuf,         // (B,K,N)
    float* __restrict__ out)                // (B,N,K*D)
{
    const int i0  = blockIdx.x * 128;
    const int k   = blockIdx.y;
    const int b   = blockIdx.z;
    const int tid = threadIdx.x;
    const int w   = tid >> 6;
    const int l   = tid & 63;
    const int q   = l >> 4;
    const int r16 = l & 15;
    const int iglob = i0 + w * 16 + r16;

    __shared__ f16 sh[2][8192];     // 2 x 16KB wht stage
    __shared__ float tl[NN];        // t * log2e, 8KB
    char* shb = (char*)&sh[0][0];

    const float* __restrict__ trow = tbuf + (b * NK + k) * NN;
    {   // stage t*log2e (coalesced, once)
        float4 tv = *(const float4*)(trow + tid * 4);
        float4 ts = {tv.x * LOG2E, tv.y * LOG2E, tv.z * LOG2E, tv.w * LOG2E};
        *(float4*)&tl[tid * 4] = ts;
    }

    const float s_lane = sbuf[(b * NK + k) * NN + iglob];
    const float shift  = fmaxf(s_lane, 0.f) + NEG * fminf(s_lane, 0.f);
    const float sp2    = (s_lane - shift) * LOG2E;
    const float c22    = -0.8f * shift * LOG2E;
    const char* gtiles = (const char*)(wht + (size_t)(b * NK + k) * 64 * 2048);
    const unsigned int* __restrict__ abrow = abit + (size_t)(b * NN + iglob) * 64;

    float denom = 0.f;
    f32x4 acc[4];
#pragma unroll
    for (int dt = 0; dt < 4; ++dt) acc[dt] = (f32x4){0.f, 0.f, 0.f, 0.f};

#define STAGE16(bb, it)                                                        \
    do {                                                                       \
        __builtin_amdgcn_global_load_lds(                                      \
            (const __attribute__((address_space(1))) void*)(gtiles +           \
                (size_t)(it) * 16384 + tid * 16),                              \
            (__attribute__((address_space(3))) void*)(shb + (bb) * 16384 +     \
                w * 1024), 16, 0, 0);                                          \
        __builtin_amdgcn_global_load_lds(                                      \
            (const __attribute__((address_space(1))) void*)(gtiles +           \
                (size_t)(it) * 16384 + 8192 + tid * 16),                       \
            (__attribute__((address_space(3))) void*)(shb + (bb) * 16384 +     \
                8192 + w * 1024), 16, 0, 0);                                   \
    } while (0)

    STAGE16(0, 0);
    uint4 ab_cur = *(const uint4*)abrow;

    for (int it = 0; it < 16; ++it) {
        __syncthreads();   // stage(it) landed; everyone done with other buf
        uint4 ab_nxt = ab_cur;
        if (it < 15) {
            STAGE16((it + 1) & 1, it + 1);
            ab_nxt = *(const uint4*)(abrow + (it + 1) * 4);
        }
        const char* lbase = shb + (it & 1) * 16384;
        const unsigned int ab_arr[4] = {ab_cur.x, ab_cur.y, ab_cur.z, ab_cur.w};
#pragma unroll
        for (int h = 0; h < 4; ++h) {
            const unsigned int bits = ab_arr[h];
            const int tb = it * 128 + h * 32;
            float4 tt0 = *(const float4*)&tl[tb + q * 4];
            float4 tt1 = *(const float4*)&tl[tb + 16 + q * 4];
            float ta[4] = {tt0.x, tt0.y, tt0.z, tt0.w};
            float tc[4] = {tt1.x, tt1.y, tt1.z, tt1.w};
            float w0[4], w1[4];
#pragma unroll
            for (int e = 0; e < 4; ++e) {
                float u0 = sp2 + ta[e];
                float g0 = fmaxf(u0, __builtin_fmaf(NEG, u0, c22));
                float x0 = __builtin_exp2f(g0);
                w0[e] = (bits & (1u << (q * 4 + e))) ? x0 : 0.f;
                float u1 = sp2 + tc[e];
                float g1 = fmaxf(u1, __builtin_fmaf(NEG, u1, c22));
                float x1 = __builtin_exp2f(g1);
                w1[e] = (bits & (1u << (16 + q * 4 + e))) ? x1 : 0.f;
                denom += w0[e] + w1[e];
            }
            f16x4 pa0 = {(f16)w0[0], (f16)w0[1], (f16)w0[2], (f16)w0[3]};
            f16x4 pa1 = {(f16)w1[0], (f16)w1[1], (f16)w1[2], (f16)w1[3]};
            const char* lb = lbase + h * 4096;
#pragma unroll
            for (int dt = 0; dt < 4; ++dt) {
                int d = dt * 16 + r16;
                f16x8 v8 = *(const f16x8*)(lb + d * 64 + ((q ^ sz2(d)) << 4));
                f16x4 bf0 = __builtin_shufflevector(v8, v8, 0, 1, 2, 3);
                f16x4 bf1 = __builtin_shufflevector(v8, v8, 4, 5, 6, 7);
                acc[dt] = __builtin_amdgcn_mfma_f32_16x16x16f16(pa0, bf0,
                                                                acc[dt], 0, 0, 0);
                acc[dt] = __builtin_amdgcn_mfma_f32_16x16x16f16(pa1, bf1,
                                                                acc[dt], 0, 0, 0);
            }
        }
        ab_cur = ab_nxt;
    }
#undef STAGE16

    // row denominators: reduce across quarter-groups
    denom += __shfl_xor(denom, 16);
    denom += __shfl_xor(denom, 32);

#pragma unroll
    for (int rr = 0; rr < 4; ++rr) {
        int irow = q * 4 + rr;                       // C row
        float dd  = __shfl(denom, (l & 48) | irow);
        float inv = 1.f / (dd + 1e-10f);
#pragma unroll
        for (int dt = 0; dt < 4; ++dt)
            out[((size_t)(b * NN) + i0 + w * 16 + irow) * (NK * ND) +
                k * ND + dt * 16 + r16] = acc[dt][rr] * inv;
    }
}

extern "C" void kernel_launch(void* const* d_in, const int* in_sizes, int n_in,
                              void* d_out, int out_size, void* d_ws, size_t ws_size,
                              hipStream_t stream) {
    const float* x     = (const float*)d_in[0];
    const int*   adj   = (const int*)d_in[1];
    const float* Wm    = (const float*)d_in[2];
    const float* a_src = (const float*)d_in[3];
    const float* a_dst = (const float*)d_in[4];
    float* out = (float*)d_out;

    char* ws = (char*)d_ws;
    f16*   wht  = (f16*)ws;                                   // 4 MiB
    float* sbuf = (float*)(ws + (4u << 20));                  // 128 KiB
    float* tbuf = (float*)(ws + (4u << 20) + (128u << 10));   // 128 KiB
    unsigned int* abit = (unsigned int*)(ws + (4u << 20) + (256u << 10)); // 2 MiB

    k0_pack<<<dim3(NB * NN / 4), 256, 0, stream>>>(adj, abit);
    k1_gemm<<<dim3(16, NK, NB), 256, 0, stream>>>(x, Wm, a_src, a_dst, wht, sbuf, tbuf);
    k2_attn<<<dim3(NN / 128, NK, NB), 512, 0, stream>>>(abit, wht, sbuf, tbuf, out);
}

// Round 5
// 50.451 us; speedup vs baseline: 3.3326x; 1.3282x over previous
//
#include <hip/hip_runtime.h>

#define NB 4
#define NN 2048
#define NF 256
#define NK 4
#define ND 64
#define NEG 0.2f
#define LOG2E 1.4426950408889634f

typedef _Float16 f16;
typedef _Float16 f16x4 __attribute__((ext_vector_type(4)));
typedef _Float16 f16x8 __attribute__((ext_vector_type(8)));
typedef float f32x4 __attribute__((ext_vector_type(4)));

// 2-bit slot swizzle for the wht tile layout (must match k1 store / k2 read)
__device__ __forceinline__ int sz2(int d) { return ((d >> 1) ^ (d >> 3)) & 3; }

// ---------------------------------------------------------------------------
// K01: merged k1 (GEMM, blocks 0..255) + k0 (adj bit-pack, blocks 256..2303).
// k1 blocks launch first so their compute overlaps k0's HBM-bound phase.
//
// k1: Wh^T = (x @ W)^T per (b,k), f16, tile-major + pair-packed + swizzled:
//   tile jt (32 j, 4KB) at wht + ((b*NK+k)*64 + jt)*2048 elems; within tile
//   elem(d, j5) at d*32 + ((qj ^ sz2(d))<<3) + (j5>>4)*4 + (j5&3), qj=(j5>>2)&3.
//   Epilogue: s = Wh a_src -> sbuf; t = Wh a_dst -> E=exp(t), F=exp(0.2t).
// k0: abit[b][i][jw] = bits of (adj>0 | I), 64 words/row.
// ---------------------------------------------------------------------------
__global__ __launch_bounds__(256) void k01(
    const float* __restrict__ x,      // (B,N,F)
    const int*   __restrict__ adj,    // (B,N,N)
    const float* __restrict__ Wm,     // (K,F,D)
    const float* __restrict__ a_src,  // (K,D)
    const float* __restrict__ a_dst,  // (K,D)
    unsigned int* __restrict__ abit,  // (B,N,64)
    f16* __restrict__ wht,            // tile-major, see above
    float* __restrict__ sbuf,         // (B,K,N)
    float* __restrict__ ebuf,         // (B,K,N) exp(t)
    float* __restrict__ fbuf)         // (B,K,N) exp(0.2 t)
{
    __shared__ f16 wt[64 * 256];  // k1 only: W^T, xor-swizzled in f

    const int bx  = blockIdx.x;
    const int tid = threadIdx.x;

    if (bx >= 256) {
        // ---------------- k0: bit-pack ----------------
        const int row = (bx - 256) * 4 + (tid >> 6);  // b*NN + i
        const int l   = tid & 63;
        const int i   = row & (NN - 1);
        const int* __restrict__ ar = adj + (size_t)row * NN;

        int v[32];
#pragma unroll
        for (int c = 0; c < 32; ++c) v[c] = ar[c * 64 + l];

        unsigned int kx = 0, ky = 0;
#pragma unroll
        for (int c = 0; c < 32; ++c) {
            unsigned long long m = __ballot(v[c] > 0);
            if (l == c) { kx = (unsigned int)m; ky = (unsigned int)(m >> 32); }
        }
        if (l == (i >> 6)) {          // self-loop bit
            unsigned int sb = 1u << (i & 31);
            if (((i >> 5) & 1) == 0) kx |= sb; else ky |= sb;
        }
        if (l < 32) {
            uint2 kk; kk.x = kx; kk.y = ky;
            *(uint2*)&abit[(size_t)row * 64 + l * 2] = kk;
        }
        return;
    }

    // ---------------- k1: GEMM ----------------
    const int gx  = bx & 15;      // n-group of 128
    const int k   = (bx >> 4) & 3;
    const int b   = bx >> 6;
    const int wv  = tid >> 6;
    const int l   = tid & 63;
    const int q   = l >> 4;
    const int r16 = l & 15;

    for (int fc = 0; fc < 64; ++fc) {
        int f = fc * 4 + wv;
        int d = l;
        wt[d * 256 + (f ^ ((d & 7) << 3))] = (f16)Wm[(k * NF + f) * ND + d];
    }
    __syncthreads();

    const int ncol0 = gx * 128 + wv * 32;
    f32x4 acc[2][4];
#pragma unroll
    for (int nt = 0; nt < 2; ++nt)
#pragma unroll
        for (int dt = 0; dt < 4; ++dt)
            acc[nt][dt] = (f32x4){0.f, 0.f, 0.f, 0.f};

    for (int fs = 0; fs < 16; ++fs) {           // K-steps of 16
        const int f0 = fs * 16 + q * 4;
        f16x4 af[4];
#pragma unroll
        for (int dt = 0; dt < 4; ++dt) {
            int d = dt * 16 + r16;
            af[dt] = *(const f16x4*)&wt[d * 256 + (f0 ^ ((d & 7) << 3))];
        }
#pragma unroll
        for (int nt = 0; nt < 2; ++nt) {
            int n = ncol0 + nt * 16 + r16;
            float4 xv = *(const float4*)&x[((size_t)(b * NN + n)) * NF + f0];
            f16x4 bf = {(f16)xv.x, (f16)xv.y, (f16)xv.z, (f16)xv.w};
#pragma unroll
            for (int dt = 0; dt < 4; ++dt)
                acc[nt][dt] = __builtin_amdgcn_mfma_f32_16x16x16f16(
                    af[dt], bf, acc[nt][dt], 0, 0, 0);
        }
    }

    float asv[4][4], adv[4][4];
#pragma unroll
    for (int dt = 0; dt < 4; ++dt)
#pragma unroll
        for (int rr = 0; rr < 4; ++rr) {
            int d = dt * 16 + q * 4 + rr;
            asv[dt][rr] = a_src[k * ND + d];
            adv[dt][rr] = a_dst[k * ND + d];
        }

    const int jt = gx * 4 + wv;  // this wave's 32-col tile index
    f16* __restrict__ tile = wht + ((size_t)(b * NK + k) * 64 + jt) * 2048;
    const int qj = r16 >> 2, ee = r16 & 3;

#pragma unroll
    for (int nt = 0; nt < 2; ++nt) {
        int n = ncol0 + nt * 16 + r16;
        float sp = 0.f, tp = 0.f;
#pragma unroll
        for (int dt = 0; dt < 4; ++dt)
#pragma unroll
            for (int rr = 0; rr < 4; ++rr) {
                float v = acc[nt][dt][rr];
                int d = dt * 16 + q * 4 + rr;    // C row = d'
                tile[d * 32 + ((qj ^ sz2(d)) << 3) + nt * 4 + ee] = (f16)v;
                sp += v * asv[dt][rr];
                tp += v * adv[dt][rr];
            }
        sp += __shfl_xor(sp, 16);
        sp += __shfl_xor(sp, 32);
        tp += __shfl_xor(tp, 16);
        tp += __shfl_xor(tp, 32);
        if (q == 0) {
            int idx = (b * NK + k) * NN + n;
            sbuf[idx] = sp;
            ebuf[idx] = __builtin_exp2f(tp * LOG2E);
            fbuf[idx] = __builtin_exp2f(0.2f * LOG2E * tp);
        }
    }
}

// ---------------------------------------------------------------------------
// K2 v5: fused masked-softmax attention, exp-free inner loop + j-split.
// w_ij = exp(lrelu(s_i+t_j) - lrelu(s_i)) = max(A_i*E_j, B_i*F_j) since
// lrelu(x)=max(x,0.2x) and exp is monotone. A,B per-lane consts; E,F in LDS.
// Block = 512 thr = 8 waves = 4 row-waves (64 i-rows) x 2 j-chunks (1024 j).
// Per chunk-iter (64 j): one 8KB double-buffered global_load_lds stage, adj
// mask bits prefetched in regs, 4 VALU-lite score ops/elem, MFMA accumulate.
// LDS combine of the two chunks at the end. Grid 512 = 2 blocks/CU.
// ---------------------------------------------------------------------------
__global__ __launch_bounds__(512) void k2_attn(
    const unsigned int* __restrict__ abit,  // (B,N,64) bit-mask
    const f16* __restrict__ wht,            // tile-major pair-packed
    const float* __restrict__ sbuf,         // (B,K,N)
    const float* __restrict__ ebuf,         // (B,K,N)
    const float* __restrict__ fbuf,         // (B,K,N)
    float* __restrict__ out)                // (B,N,K*D)
{
    const int i0  = blockIdx.x * 64;
    const int k   = blockIdx.y;
    const int b   = blockIdx.z;
    const int tid = threadIdx.x;
    const int w   = tid >> 6;
    const int c   = w >> 2;          // j-chunk 0/1
    const int rw  = w & 3;           // row-wave 0..3
    const int l   = tid & 63;
    const int q   = l >> 4;
    const int r16 = l & 15;
    const int iglob = i0 + rw * 16 + r16;

    // LDS pool: [0,32KB) stage (chunk c at c*16KB, 2 bufs of 8KB);
    // [32KB,40KB) el; [40KB,48KB) fl; [48KB,+512B) dden; stash reuses [0,16KB)
    __shared__ char pool[49664];
    float* el   = (float*)(pool + 32768);
    float* fl   = (float*)(pool + 40960);
    float* dden = (float*)(pool + 49152);

    {   // stage E/F (full 2048, coalesced, once)
        const float* eb = ebuf + (b * NK + k) * NN;
        const float* fb = fbuf + (b * NK + k) * NN;
        *(float4*)&el[tid * 4] = *(const float4*)&eb[tid * 4];
        *(float4*)&fl[tid * 4] = *(const float4*)&fb[tid * 4];
    }

    const float s  = sbuf[(b * NK + k) * NN + iglob];
    const float Af = __builtin_exp2f(0.8f * LOG2E * fminf(s, 0.f));   // <= 1
    const float Bf = __builtin_exp2f(-0.8f * LOG2E * fmaxf(s, 0.f));  // <= 1
    const char* gtiles = (const char*)(wht + (size_t)(b * NK + k) * 64 * 2048);
    const unsigned int* __restrict__ abrow =
        abit + (size_t)(b * NN + iglob) * 64 + c * 32;

    float denom = 0.f;
    f32x4 acc[4];
#pragma unroll
    for (int dt = 0; dt < 4; ++dt) acc[dt] = (f32x4){0.f, 0.f, 0.f, 0.f};

#define STAGE8(bb, it)                                                         \
    do {                                                                       \
        const char* gsrc = gtiles + (size_t)(c * 1024 + (it) * 64) * 128 +     \
                           (tid & 255) * 16;                                   \
        char* ldst = pool + c * 16384 + (bb) * 8192 + (w & 3) * 1024;          \
        __builtin_amdgcn_global_load_lds(                                      \
            (const __attribute__((address_space(1))) void*)gsrc,               \
            (__attribute__((address_space(3))) void*)ldst, 16, 0, 0);          \
        __builtin_amdgcn_global_load_lds(                                      \
            (const __attribute__((address_space(1))) void*)(gsrc + 4096),      \
            (__attribute__((address_space(3))) void*)(ldst + 4096), 16, 0, 0); \
    } while (0)

    STAGE8(0, 0);
    uint2 ab = *(const uint2*)abrow;

    for (int it = 0; it < 16; ++it) {
        __syncthreads();   // stage(it) landed; all done with the other buf
        uint2 ab_n = ab;
        if (it < 15) {
            STAGE8((it + 1) & 1, it + 1);
            ab_n = *(const uint2*)(abrow + (it + 1) * 2);
        }
        const char* lb0 = pool + c * 16384 + (it & 1) * 8192;
#pragma unroll
        for (int h = 0; h < 2; ++h) {
            const unsigned int bits = h ? ab.y : ab.x;
            const unsigned int bs = bits >> (q * 4);
            const int tb = c * 1024 + it * 64 + h * 32;
            float4 e0 = *(const float4*)&el[tb + q * 4];
            float4 e1 = *(const float4*)&el[tb + 16 + q * 4];
            float4 f0 = *(const float4*)&fl[tb + q * 4];
            float4 f1 = *(const float4*)&fl[tb + 16 + q * 4];
            float ea[4] = {e0.x, e0.y, e0.z, e0.w};
            float eb[4] = {e1.x, e1.y, e1.z, e1.w};
            float fa[4] = {f0.x, f0.y, f0.z, f0.w};
            float fb[4] = {f1.x, f1.y, f1.z, f1.w};
            float w0[4], w1[4];
#pragma unroll
            for (int e = 0; e < 4; ++e) {
                float wa = fmaxf(Af * ea[e], Bf * fa[e]);
                w0[e] = (bs & (1u << e)) ? wa : 0.f;
                float wb = fmaxf(Af * eb[e], Bf * fb[e]);
                w1[e] = (bs & (1u << (16 + e))) ? wb : 0.f;
            }
            denom += ((w0[0] + w0[1]) + (w0[2] + w0[3])) +
                     ((w1[0] + w1[1]) + (w1[2] + w1[3]));
            f16x4 pa0 = {(f16)w0[0], (f16)w0[1], (f16)w0[2], (f16)w0[3]};
            f16x4 pa1 = {(f16)w1[0], (f16)w1[1], (f16)w1[2], (f16)w1[3]};
            const char* lb = lb0 + h * 4096;
#pragma unroll
            for (int dt = 0; dt < 4; ++dt) {
                int d = dt * 16 + r16;
                f16x8 v8 = *(const f16x8*)(lb + d * 64 + ((q ^ sz2(d)) << 4));
                f16x4 bf0 = __builtin_shufflevector(v8, v8, 0, 1, 2, 3);
                f16x4 bf1 = __builtin_shufflevector(v8, v8, 4, 5, 6, 7);
                acc[dt] = __builtin_amdgcn_mfma_f32_16x16x16f16(pa0, bf0,
                                                                acc[dt], 0, 0, 0);
                acc[dt] = __builtin_amdgcn_mfma_f32_16x16x16f16(pa1, bf1,
                                                                acc[dt], 0, 0, 0);
            }
        }
        ab = ab_n;
    }
#undef STAGE8

    // per-row denominators within this chunk
    denom += __shfl_xor(denom, 16);
    denom += __shfl_xor(denom, 32);

    __syncthreads();                 // all compute done; stage area reusable
    float* stash = (float*)pool;     // 16KB: [rw*4+dt][lane*4]
    if (c == 1) {
#pragma unroll
        for (int dt = 0; dt < 4; ++dt)
            *(f32x4*)&stash[(rw * 4 + dt) * 256 + l * 4] = acc[dt];
    }
    if (l < 16) dden[c * 64 + rw * 16 + l] = denom;
    __syncthreads();

    if (c == 0) {
#pragma unroll
        for (int dt = 0; dt < 4; ++dt)
            acc[dt] += *(const f32x4*)&stash[(rw * 4 + dt) * 256 + l * 4];
#pragma unroll
        for (int rr = 0; rr < 4; ++rr) {
            int irow = q * 4 + rr;
            float dd = dden[rw * 16 + irow] + dden[64 + rw * 16 + irow];
            float inv = 1.f / (dd + 1e-10f);
#pragma unroll
            for (int dt = 0; dt < 4; ++dt)
                out[((size_t)(b * NN) + i0 + rw * 16 + irow) * (NK * ND) +
                    k * ND + dt * 16 + r16] = acc[dt][rr] * inv;
        }
    }
}

extern "C" void kernel_launch(void* const* d_in, const int* in_sizes, int n_in,
                              void* d_out, int out_size, void* d_ws, size_t ws_size,
                              hipStream_t stream) {
    const float* x     = (const float*)d_in[0];
    const int*   adj   = (const int*)d_in[1];
    const float* Wm    = (const float*)d_in[2];
    const float* a_src = (const float*)d_in[3];
    const float* a_dst = (const float*)d_in[4];
    float* out = (float*)d_out;

    char* ws = (char*)d_ws;
    f16*   wht  = (f16*)ws;                                   // 4 MiB
    float* sbuf = (float*)(ws + (4u << 20));                  // 128 KiB
    float* ebuf = (float*)(ws + (4u << 20) + (128u << 10));   // 128 KiB
    float* fbuf = (float*)(ws + (4u << 20) + (256u << 10));   // 128 KiB
    unsigned int* abit = (unsigned int*)(ws + (4u << 20) + (384u << 10)); // 2 MiB

    k01<<<dim3(256 + NB * NN / 4), 256, 0, stream>>>(
        x, adj, Wm, a_src, a_dst, abit, wht, sbuf, ebuf, fbuf);
    k2_attn<<<dim3(NN / 64, NK, NB), 512, 0, stream>>>(
        abit, wht, sbuf, ebuf, fbuf, out);
}

// Round 6
// 47.758 us; speedup vs baseline: 3.5205x; 1.0564x over previous
//
#include <hip/hip_runtime.h>

#define NB 4
#define NN 2048
#define NF 256
#define NK 4
#define ND 64
#define NEG 0.2f
#define LOG2E 1.4426950408889634f

typedef _Float16 f16;
typedef _Float16 f16x4 __attribute__((ext_vector_type(4)));
typedef _Float16 f16x8 __attribute__((ext_vector_type(8)));
typedef float f32x4 __attribute__((ext_vector_type(4)));

// 2-bit slot swizzle for the wht tile layout (must match k1 store / k2 read)
__device__ __forceinline__ int sz2(int d) { return ((d >> 1) ^ (d >> 3)) & 3; }

// ---------------------------------------------------------------------------
// K01: merged k1 (GEMM, blocks 0..255) + k0 (adj bit-pack, blocks 256..2303).
// k1: Wh^T = (x @ W)^T per (b,k), f16, tile-major + pair-packed + swizzled:
//   tile jt (32 j, 4KB) at wht + ((b*NK+k)*64 + jt)*2048 elems; within tile
//   elem(d, j5) at d*32 + ((qj ^ sz2(d))<<3) + (j5>>4)*4 + (j5&3), qj=(j5>>2)&3.
//   Epilogue: s = Wh a_src -> sbuf; t = Wh a_dst -> E=exp(t), F=exp(0.2t).
// k0: abit[b][i][jw] = bits of (adj>0 | I), 64 words/row.
// ---------------------------------------------------------------------------
__global__ __launch_bounds__(256) void k01(
    const float* __restrict__ x,      // (B,N,F)
    const int*   __restrict__ adj,    // (B,N,N)
    const float* __restrict__ Wm,     // (K,F,D)
    const float* __restrict__ a_src,  // (K,D)
    const float* __restrict__ a_dst,  // (K,D)
    unsigned int* __restrict__ abit,  // (B,N,64)
    f16* __restrict__ wht,            // tile-major, see above
    float* __restrict__ sbuf,         // (B,K,N)
    float* __restrict__ ebuf,         // (B,K,N) exp(t)
    float* __restrict__ fbuf)         // (B,K,N) exp(0.2 t)
{
    __shared__ f16 wt[64 * 256];  // k1 only: W^T, xor-swizzled in f

    const int bx  = blockIdx.x;
    const int tid = threadIdx.x;

    if (bx >= 256) {
        // ---------------- k0: bit-pack ----------------
        const int row = (bx - 256) * 4 + (tid >> 6);  // b*NN + i
        const int l   = tid & 63;
        const int i   = row & (NN - 1);
        const int* __restrict__ ar = adj + (size_t)row * NN;

        int v[32];
#pragma unroll
        for (int c = 0; c < 32; ++c) v[c] = ar[c * 64 + l];

        unsigned int kx = 0, ky = 0;
#pragma unroll
        for (int c = 0; c < 32; ++c) {
            unsigned long long m = __ballot(v[c] > 0);
            if (l == c) { kx = (unsigned int)m; ky = (unsigned int)(m >> 32); }
        }
        if (l == (i >> 6)) {          // self-loop bit
            unsigned int sb = 1u << (i & 31);
            if (((i >> 5) & 1) == 0) kx |= sb; else ky |= sb;
        }
        if (l < 32) {
            uint2 kk; kk.x = kx; kk.y = ky;
            *(uint2*)&abit[(size_t)row * 64 + l * 2] = kk;
        }
        return;
    }

    // ---------------- k1: GEMM ----------------
    const int gx  = bx & 15;      // n-group of 128
    const int k   = (bx >> 4) & 3;
    const int b   = bx >> 6;
    const int wv  = tid >> 6;
    const int l   = tid & 63;
    const int q   = l >> 4;
    const int r16 = l & 15;

    for (int fc = 0; fc < 64; ++fc) {
        int f = fc * 4 + wv;
        int d = l;
        wt[d * 256 + (f ^ ((d & 7) << 3))] = (f16)Wm[(k * NF + f) * ND + d];
    }
    __syncthreads();

    const int ncol0 = gx * 128 + wv * 32;
    f32x4 acc[2][4];
#pragma unroll
    for (int nt = 0; nt < 2; ++nt)
#pragma unroll
        for (int dt = 0; dt < 4; ++dt)
            acc[nt][dt] = (f32x4){0.f, 0.f, 0.f, 0.f};

    for (int fs = 0; fs < 16; ++fs) {           // K-steps of 16
        const int f0 = fs * 16 + q * 4;
        f16x4 af[4];
#pragma unroll
        for (int dt = 0; dt < 4; ++dt) {
            int d = dt * 16 + r16;
            af[dt] = *(const f16x4*)&wt[d * 256 + (f0 ^ ((d & 7) << 3))];
        }
#pragma unroll
        for (int nt = 0; nt < 2; ++nt) {
            int n = ncol0 + nt * 16 + r16;
            float4 xv = *(const float4*)&x[((size_t)(b * NN + n)) * NF + f0];
            f16x4 bf = {(f16)xv.x, (f16)xv.y, (f16)xv.z, (f16)xv.w};
#pragma unroll
            for (int dt = 0; dt < 4; ++dt)
                acc[nt][dt] = __builtin_amdgcn_mfma_f32_16x16x16f16(
                    af[dt], bf, acc[nt][dt], 0, 0, 0);
        }
    }

    float asv[4][4], adv[4][4];
#pragma unroll
    for (int dt = 0; dt < 4; ++dt)
#pragma unroll
        for (int rr = 0; rr < 4; ++rr) {
            int d = dt * 16 + q * 4 + rr;
            asv[dt][rr] = a_src[k * ND + d];
            adv[dt][rr] = a_dst[k * ND + d];
        }

    const int jt = gx * 4 + wv;  // this wave's 32-col tile index
    f16* __restrict__ tile = wht + ((size_t)(b * NK + k) * 64 + jt) * 2048;
    const int qj = r16 >> 2, ee = r16 & 3;

#pragma unroll
    for (int nt = 0; nt < 2; ++nt) {
        int n = ncol0 + nt * 16 + r16;
        float sp = 0.f, tp = 0.f;
#pragma unroll
        for (int dt = 0; dt < 4; ++dt)
#pragma unroll
            for (int rr = 0; rr < 4; ++rr) {
                float v = acc[nt][dt][rr];
                int d = dt * 16 + q * 4 + rr;    // C row = d'
                tile[d * 32 + ((qj ^ sz2(d)) << 3) + nt * 4 + ee] = (f16)v;
                sp += v * asv[dt][rr];
                tp += v * adv[dt][rr];
            }
        sp += __shfl_xor(sp, 16);
        sp += __shfl_xor(sp, 32);
        tp += __shfl_xor(tp, 16);
        tp += __shfl_xor(tp, 32);
        if (q == 0) {
            int idx = (b * NK + k) * NN + n;
            sbuf[idx] = sp;
            ebuf[idx] = __builtin_exp2f(tp * LOG2E);
            fbuf[idx] = __builtin_exp2f(0.2f * LOG2E * tp);
        }
    }
}

// ---------------------------------------------------------------------------
// K2 v6: exp-free fused attention; 16x16x32 MFMA; counted-vmcnt 3-buffer
// pipeline (raw s_barrier, never vmcnt(0) in steady state); adj bits fully
// register-prefetched (only stage loads count against vmcnt).
// Block = 512 thr = 8 waves = 4 row-waves (64 i) x 2 j-chunks (1024 j).
// w_ij = exp(lrelu(s_i+t_j)-lrelu(s_i)) = max(A_i*E_j, B_i*F_j).
// ---------------------------------------------------------------------------
__global__ __launch_bounds__(512, 4) void k2_attn(
    const unsigned int* __restrict__ abit,  // (B,N,64) bit-mask
    const f16* __restrict__ wht,            // tile-major pair-packed
    const float* __restrict__ sbuf,         // (B,K,N)
    const float* __restrict__ ebuf,         // (B,K,N)
    const float* __restrict__ fbuf,         // (B,K,N)
    float* __restrict__ out)                // (B,N,K*D)
{
    const int i0  = blockIdx.x * 64;
    const int k   = blockIdx.y;
    const int b   = blockIdx.z;
    const int tid = threadIdx.x;
    const int w   = tid >> 6;
    const int c   = w >> 2;          // j-chunk 0/1
    const int rw  = w & 3;           // row-wave 0..3
    const int l   = tid & 63;
    const int q   = l >> 4;
    const int r16 = l & 15;
    const int iglob = i0 + rw * 16 + r16;

    // LDS pool: [0,48KB) stage (chunk c at c*24KB, 3 bufs of 8KB);
    // [48,56K) el; [56,64K) fl; [64K,+512B) dden; stash reuses [0,16KB)
    __shared__ char pool[66048];
    float* el   = (float*)(pool + 49152);
    float* fl   = (float*)(pool + 57344);
    float* dden = (float*)(pool + 65536);

    // adj bits for this lane's row, both K=16 halves of all 16 iters
    const unsigned int* __restrict__ abrow =
        abit + (size_t)(b * NN + iglob) * 64 + c * 32;
    uint2 abx[16];
#pragma unroll
    for (int it = 0; it < 16; ++it) abx[it] = *(const uint2*)(abrow + it * 2);

    {   // stage E/F (full 2048 row, coalesced, once)
        const float* eb = ebuf + (b * NK + k) * NN;
        const float* fb = fbuf + (b * NK + k) * NN;
        *(float4*)&el[tid * 4] = *(const float4*)&eb[tid * 4];
        *(float4*)&fl[tid * 4] = *(const float4*)&fb[tid * 4];
    }

    const float s  = sbuf[(b * NK + k) * NN + iglob];
    const float Af = __builtin_exp2f(0.8f * LOG2E * fminf(s, 0.f));   // <= 1
    const float Bf = __builtin_exp2f(-0.8f * LOG2E * fmaxf(s, 0.f));  // <= 1
    const char* gtiles = (const char*)(wht + (size_t)(b * NK + k) * 64 * 2048);

    float denom = 0.f;
    f32x4 acc[4];
#pragma unroll
    for (int dt = 0; dt < 4; ++dt) acc[dt] = (f32x4){0.f, 0.f, 0.f, 0.f};

#define STAGE8(bb, it)                                                         \
    do {                                                                       \
        const char* gsrc = gtiles + (size_t)(c * 1024 + (it) * 64) * 128 +     \
                           (tid & 255) * 16;                                   \
        char* ldst = pool + c * 24576 + (bb) * 8192 + (w & 3) * 1024;          \
        __builtin_amdgcn_global_load_lds(                                      \
            (const __attribute__((address_space(1))) void*)gsrc,               \
            (__attribute__((address_space(3))) void*)ldst, 16, 0, 0);          \
        __builtin_amdgcn_global_load_lds(                                      \
            (const __attribute__((address_space(1))) void*)(gsrc + 4096),      \
            (__attribute__((address_space(3))) void*)(ldst + 4096), 16, 0, 0); \
    } while (0)

    STAGE8(0, 0);
    STAGE8(1, 1);

#pragma unroll
    for (int it = 0; it < 16; ++it) {
        // stage(it) landed when only stage(it+1)'s 2 loads are outstanding
        if (it < 15)
            asm volatile("s_waitcnt vmcnt(2) lgkmcnt(0)" ::: "memory");
        else
            asm volatile("s_waitcnt vmcnt(0) lgkmcnt(0)" ::: "memory");
        __builtin_amdgcn_sched_barrier(0);
        __builtin_amdgcn_s_barrier();
        __builtin_amdgcn_sched_barrier(0);
        if (it < 14) STAGE8((it + 2) % 3, it + 2);   // buf freed by compute(it-1)

        const char* lb0 = pool + c * 24576 + (it % 3) * 8192;
        const uint2 ab = abx[it];
#pragma unroll
        for (int h = 0; h < 2; ++h) {
            const unsigned int bits = h ? ab.y : ab.x;
            const unsigned int bs = bits >> (q * 4);
            const int tb = c * 1024 + it * 64 + h * 32;
            float4 e0 = *(const float4*)&el[tb + q * 4];
            float4 e1 = *(const float4*)&el[tb + 16 + q * 4];
            float4 f0 = *(const float4*)&fl[tb + q * 4];
            float4 f1 = *(const float4*)&fl[tb + 16 + q * 4];
            float ea[4] = {e0.x, e0.y, e0.z, e0.w};
            float eb[4] = {e1.x, e1.y, e1.z, e1.w};
            float fa[4] = {f0.x, f0.y, f0.z, f0.w};
            float fb[4] = {f1.x, f1.y, f1.z, f1.w};
            float w0[4], w1[4];
#pragma unroll
            for (int e = 0; e < 4; ++e) {
                float wa = fmaxf(Af * ea[e], Bf * fa[e]);
                w0[e] = (bs & (1u << e)) ? wa : 0.f;
                float wb = fmaxf(Af * eb[e], Bf * fb[e]);
                w1[e] = (bs & (1u << (16 + e))) ? wb : 0.f;
            }
            denom += ((w0[0] + w0[1]) + (w0[2] + w0[3])) +
                     ((w1[0] + w1[1]) + (w1[2] + w1[3]));
            // A fragment: elems 0-3 = k half [0,16), elems 4-7 = half [16,32);
            // B (v8) packed identically by k1 -> same k-mapping cancels any HW
            // permutation inside the dot product.
            f16x8 pa = {(f16)w0[0], (f16)w0[1], (f16)w0[2], (f16)w0[3],
                        (f16)w1[0], (f16)w1[1], (f16)w1[2], (f16)w1[3]};
            const char* lb = lb0 + h * 4096;
#pragma unroll
            for (int dt = 0; dt < 4; ++dt) {
                int d = dt * 16 + r16;
                f16x8 v8 = *(const f16x8*)(lb + d * 64 + ((q ^ sz2(d)) << 4));
                acc[dt] = __builtin_amdgcn_mfma_f32_16x16x32_f16(
                    pa, v8, acc[dt], 0, 0, 0);
            }
        }
    }
#undef STAGE8

    // per-row denominators within this chunk
    denom += __shfl_xor(denom, 16);
    denom += __shfl_xor(denom, 32);

    __syncthreads();                 // all compute done; stage area reusable
    float* stash = (float*)pool;     // 16KB: [rw*4+dt][lane*4]
    if (c == 1) {
#pragma unroll
        for (int dt = 0; dt < 4; ++dt)
            *(f32x4*)&stash[(rw * 4 + dt) * 256 + l * 4] = acc[dt];
    }
    if (l < 16) dden[c * 64 + rw * 16 + l] = denom;
    __syncthreads();

    if (c == 0) {
#pragma unroll
        for (int dt = 0; dt < 4; ++dt)
            acc[dt] += *(const f32x4*)&stash[(rw * 4 + dt) * 256 + l * 4];
#pragma unroll
        for (int rr = 0; rr < 4; ++rr) {
            int irow = q * 4 + rr;
            float dd = dden[rw * 16 + irow] + dden[64 + rw * 16 + irow];
            float inv = 1.f / (dd + 1e-10f);
#pragma unroll
            for (int dt = 0; dt < 4; ++dt)
                out[((size_t)(b * NN) + i0 + rw * 16 + irow) * (NK * ND) +
                    k * ND + dt * 16 + r16] = acc[dt][rr] * inv;
        }
    }
}

extern "C" void kernel_launch(void* const* d_in, const int* in_sizes, int n_in,
                              void* d_out, int out_size, void* d_ws, size_t ws_size,
                              hipStream_t stream) {
    const float* x     = (const float*)d_in[0];
    const int*   adj   = (const int*)d_in[1];
    const float* Wm    = (const float*)d_in[2];
    const float* a_src = (const float*)d_in[3];
    const float* a_dst = (const float*)d_in[4];
    float* out = (float*)d_out;

    char* ws = (char*)d_ws;
    f16*   wht  = (f16*)ws;                                   // 4 MiB
    float* sbuf = (float*)(ws + (4u << 20));                  // 128 KiB
    float* ebuf = (float*)(ws + (4u << 20) + (128u << 10));   // 128 KiB
    float* fbuf = (float*)(ws + (4u << 20) + (256u << 10));   // 128 KiB
    unsigned int* abit = (unsigned int*)(ws + (4u << 20) + (384u << 10)); // 2 MiB

    k01<<<dim3(256 + NB * NN / 4), 256, 0, stream>>>(
        x, adj, Wm, a_src, a_dst, abit, wht, sbuf, ebuf, fbuf);
    k2_attn<<<dim3(NN / 64, NK, NB), 512, 0, stream>>>(
        abit, wht, sbuf, ebuf, fbuf, out);
}

// Round 7
// 46.380 us; speedup vs baseline: 3.6250x; 1.0297x over previous
//
#include <hip/hip_runtime.h>

#define NB 4
#define NN 2048
#define NF 256
#define NK 4
#define ND 64
#define NEG 0.2f
#define LOG2E 1.4426950408889634f

typedef _Float16 f16;
typedef _Float16 f16x4 __attribute__((ext_vector_type(4)));
typedef _Float16 f16x8 __attribute__((ext_vector_type(8)));
typedef float f32x4 __attribute__((ext_vector_type(4)));
typedef float f32x16 __attribute__((ext_vector_type(16)));

// 3-bit group swizzle for the wht slab layout (k1 store must match k2 read)
__device__ __forceinline__ int gsz(int d) { return (d ^ (d >> 3)) & 7; }

// ---------------------------------------------------------------------------
// K01: merged k1 (GEMM, blocks 0..255) + k0 (adj bit-pack, blocks 256..2303).
// k1: Wh^T = (x @ W)^T per (b,k), f16. Global layout: 32 slabs of 8KB per
//   (b,k); slab s covers j in [s*64,s*64+64):
//     elem(d, j) at s*4096 + d*64 + ((g ^ gsz(d))<<3) + (j&7),  g=(j>>3)&7
//   so K2 lane (d, hi) reads its 8-j B-fragment as ONE swizzled ds_read_b128
//   after a LINEAR global_load_lds stage.
//   Epilogue: s = Wh a_src -> sbuf; t = Wh a_dst -> E=exp(t), F=exp(0.2t).
// k0: abit[b][i][jw] = bits of (adj>0 | I), 64 words/row.
// ---------------------------------------------------------------------------
__global__ __launch_bounds__(256) void k01(
    const float* __restrict__ x,      // (B,N,F)
    const int*   __restrict__ adj,    // (B,N,N)
    const float* __restrict__ Wm,     // (K,F,D)
    const float* __restrict__ a_src,  // (K,D)
    const float* __restrict__ a_dst,  // (K,D)
    unsigned int* __restrict__ abit,  // (B,N,64)
    f16* __restrict__ wht,            // slab layout, see above
    float* __restrict__ sbuf,         // (B,K,N)
    float* __restrict__ ebuf,         // (B,K,N) exp(t)
    float* __restrict__ fbuf)         // (B,K,N) exp(0.2 t)
{
    __shared__ f16 wt[64 * 256];  // k1 only: W^T, xor-swizzled in f

    const int bx  = blockIdx.x;
    const int tid = threadIdx.x;

    if (bx >= 256) {
        // ---------------- k0: bit-pack ----------------
        const int row = (bx - 256) * 4 + (tid >> 6);  // b*NN + i
        const int l   = tid & 63;
        const int i   = row & (NN - 1);
        const int* __restrict__ ar = adj + (size_t)row * NN;

        int v[32];
#pragma unroll
        for (int c = 0; c < 32; ++c) v[c] = ar[c * 64 + l];

        unsigned int kx = 0, ky = 0;
#pragma unroll
        for (int c = 0; c < 32; ++c) {
            unsigned long long m = __ballot(v[c] > 0);
            if (l == c) { kx = (unsigned int)m; ky = (unsigned int)(m >> 32); }
        }
        if (l == (i >> 6)) {          // self-loop bit
            unsigned int sb = 1u << (i & 31);
            if (((i >> 5) & 1) == 0) kx |= sb; else ky |= sb;
        }
        if (l < 32) {
            uint2 kk; kk.x = kx; kk.y = ky;
            *(uint2*)&abit[(size_t)row * 64 + l * 2] = kk;
        }
        return;
    }

    // ---------------- k1: GEMM ----------------
    const int gx  = bx & 15;      // n-group of 128
    const int k   = (bx >> 4) & 3;
    const int b   = bx >> 6;
    const int wv  = tid >> 6;
    const int l   = tid & 63;
    const int q   = l >> 4;
    const int r16 = l & 15;

    for (int fc = 0; fc < 64; ++fc) {
        int f = fc * 4 + wv;
        int d = l;
        wt[d * 256 + (f ^ ((d & 7) << 3))] = (f16)Wm[(k * NF + f) * ND + d];
    }
    __syncthreads();

    const int ncol0 = gx * 128 + wv * 32;
    f32x4 acc[2][4];
#pragma unroll
    for (int nt = 0; nt < 2; ++nt)
#pragma unroll
        for (int dt = 0; dt < 4; ++dt)
            acc[nt][dt] = (f32x4){0.f, 0.f, 0.f, 0.f};

    for (int fs = 0; fs < 16; ++fs) {           // K-steps of 16
        const int f0 = fs * 16 + q * 4;
        f16x4 af[4];
#pragma unroll
        for (int dt = 0; dt < 4; ++dt) {
            int d = dt * 16 + r16;
            af[dt] = *(const f16x4*)&wt[d * 256 + (f0 ^ ((d & 7) << 3))];
        }
#pragma unroll
        for (int nt = 0; nt < 2; ++nt) {
            int n = ncol0 + nt * 16 + r16;
            float4 xv = *(const float4*)&x[((size_t)(b * NN + n)) * NF + f0];
            f16x4 bf = {(f16)xv.x, (f16)xv.y, (f16)xv.z, (f16)xv.w};
#pragma unroll
            for (int dt = 0; dt < 4; ++dt)
                acc[nt][dt] = __builtin_amdgcn_mfma_f32_16x16x16f16(
                    af[dt], bf, acc[nt][dt], 0, 0, 0);
        }
    }

    float asv[4][4], adv[4][4];
#pragma unroll
    for (int dt = 0; dt < 4; ++dt)
#pragma unroll
        for (int rr = 0; rr < 4; ++rr) {
            int d = dt * 16 + q * 4 + rr;
            asv[dt][rr] = a_src[k * ND + d];
            adv[dt][rr] = a_dst[k * ND + d];
        }

    const size_t obase = (size_t)(b * NK + k) * 131072;

#pragma unroll
    for (int nt = 0; nt < 2; ++nt) {
        int n  = ncol0 + nt * 16 + r16;
        int s_ = n >> 6, g = (n >> 3) & 7, e = n & 7;
        float sp = 0.f, tp = 0.f;
#pragma unroll
        for (int dt = 0; dt < 4; ++dt)
#pragma unroll
            for (int rr = 0; rr < 4; ++rr) {
                float v = acc[nt][dt][rr];
                int d = dt * 16 + q * 4 + rr;    // C row = d'
                wht[obase + s_ * 4096 + d * 64 + ((g ^ gsz(d)) << 3) + e] = (f16)v;
                sp += v * asv[dt][rr];
                tp += v * adv[dt][rr];
            }
        sp += __shfl_xor(sp, 16);
        sp += __shfl_xor(sp, 32);
        tp += __shfl_xor(tp, 16);
        tp += __shfl_xor(tp, 32);
        if (q == 0) {
            int idx = (b * NK + k) * NN + n;
            sbuf[idx] = sp;
            ebuf[idx] = __builtin_exp2f(tp * LOG2E);
            fbuf[idx] = __builtin_exp2f(0.2f * LOG2E * tp);
        }
    }
}

// ---------------------------------------------------------------------------
// K2 v7: exp-free fused attention, 32 rows/wave via mfma_f32_32x32x16_f16.
// Block = 1024 thr = 16 waves = 4 row-waves (128 i) x 4 j-chunks (512 j).
// Grid 256 = 1 block/CU (LDS 114KB). Per iter (64 j): one 8KB slab staged per
// chunk (3-buf, counted vmcnt, raw s_barrier), adj bits register-prefetched,
// w_ij = max(Af_i*E_j, Bf_i*F_j) (exp factored out), 8 MFMA 32x32x16.
// A/B both packed with k = hi*8+e -> identical k-map cancels HW permutation.
// In-LDS combine of the 4 chunks at the end (stash reuses stage area).
// ---------------------------------------------------------------------------
__global__ __launch_bounds__(1024, 4) void k2_attn(
    const unsigned int* __restrict__ abit,  // (B,N,64) bit-mask
    const f16* __restrict__ wht,            // slab layout
    const float* __restrict__ sbuf,         // (B,K,N)
    const float* __restrict__ ebuf,         // (B,K,N)
    const float* __restrict__ fbuf,         // (B,K,N)
    float* __restrict__ out)                // (B,N,K*D)
{
    const int i0  = blockIdx.x * 128;
    const int k   = blockIdx.y;
    const int b   = blockIdx.z;
    const int tid = threadIdx.x;
    const int w   = tid >> 6;
    const int c   = w >> 2;          // j-chunk 0..3
    const int rw  = w & 3;           // row-wave 0..3
    const int l   = tid & 63;
    const int r32 = l & 31;
    const int hi  = l >> 5;
    const int iglob = i0 + rw * 32 + r32;

    // LDS: [0,96K) stage (chunk c at c*24K, 3 bufs of 8K; reused as stash);
    // [96K,104K) el; [104K,112K) fl; [112K,+2K) dden
    __shared__ __attribute__((aligned(16))) char pool[116736];
    float* el   = (float*)(pool + 98304);
    float* fl   = (float*)(pool + 106496);
    float* dden = (float*)(pool + 114688);

    // adj bits: 8 iters x 64 bits for this lane's row, this chunk
    const unsigned int* __restrict__ abrow =
        abit + (size_t)(b * NN + iglob) * 64 + c * 16;
    uint2 abx[8];
#pragma unroll
    for (int it = 0; it < 8; ++it) abx[it] = *(const uint2*)(abrow + it * 2);

    {   // stage E/F (full 2048 row, once)
        const float* eb = ebuf + (b * NK + k) * NN;
        const float* fb = fbuf + (b * NK + k) * NN;
        int t5 = tid & 511;
        if (tid < 512) *(float4*)&el[t5 * 4] = *(const float4*)&eb[t5 * 4];
        else           *(float4*)&fl[t5 * 4] = *(const float4*)&fb[t5 * 4];
    }

    const float s  = sbuf[(b * NK + k) * NN + iglob];
    const float Af = __builtin_exp2f(0.8f * LOG2E * fminf(s, 0.f));   // <= 1
    const float Bf = __builtin_exp2f(-0.8f * LOG2E * fmaxf(s, 0.f));  // <= 1
    const char* gtiles = (const char*)wht + (size_t)(b * NK + k) * 262144;

    float denom = 0.f;
    f32x16 acc[2];
#pragma unroll
    for (int dh = 0; dh < 2; ++dh)
#pragma unroll
        for (int z = 0; z < 16; ++z) acc[dh][z] = 0.f;

#define STAGE8(bb, it)                                                         \
    do {                                                                       \
        const char* gsrc = gtiles + (size_t)(c * 8 + (it)) * 8192 +            \
                           (tid & 255) * 16;                                   \
        char* ldst = pool + c * 24576 + (bb) * 8192 + (tid & 255) * 16;        \
        __builtin_amdgcn_global_load_lds(                                      \
            (const __attribute__((address_space(1))) void*)gsrc,               \
            (__attribute__((address_space(3))) void*)ldst, 16, 0, 0);          \
        __builtin_amdgcn_global_load_lds(                                      \
            (const __attribute__((address_space(1))) void*)(gsrc + 4096),      \
            (__attribute__((address_space(3))) void*)(ldst + 4096), 16, 0, 0); \
    } while (0)

    // pin: all prefetch loads (abx, E/F, s) issue BEFORE the stage loads,
    // so vmcnt(2) in-loop implies stage(it) has landed.
    __builtin_amdgcn_sched_barrier(0);
    STAGE8(0, 0);
    STAGE8(1, 1);

#pragma unroll
    for (int it = 0; it < 8; ++it) {
        if (it < 7) asm volatile("s_waitcnt vmcnt(2) lgkmcnt(0)" ::: "memory");
        else        asm volatile("s_waitcnt vmcnt(0) lgkmcnt(0)" ::: "memory");
        __builtin_amdgcn_sched_barrier(0);
        __builtin_amdgcn_s_barrier();
        __builtin_amdgcn_sched_barrier(0);
        if (it < 6) STAGE8((it + 2) % 3, it + 2);  // buf freed by compute(it-1)

        const char* lb = pool + c * 24576 + (it % 3) * 8192;
        const uint2 ab = abx[it];
#pragma unroll
        for (int jj = 0; jj < 4; ++jj) {
            const int jts = (jj + c) & 3;          // per-chunk rotation
            const unsigned int word  = (jts & 2) ? ab.y : ab.x;
            const unsigned int mbyte = (word >> (((jts & 1) << 4) + (hi << 3))) & 0xffu;
            const int jb = c * 512 + it * 64 + jts * 16 + hi * 8;
            float4 e0 = *(const float4*)&el[jb];
            float4 e1 = *(const float4*)&el[jb + 4];
            float4 f0 = *(const float4*)&fl[jb];
            float4 f1 = *(const float4*)&fl[jb + 4];
            float ev[8] = {e0.x, e0.y, e0.z, e0.w, e1.x, e1.y, e1.z, e1.w};
            float fv[8] = {f0.x, f0.y, f0.z, f0.w, f1.x, f1.y, f1.z, f1.w};
            float wv[8];
#pragma unroll
            for (int e = 0; e < 8; ++e) {
                float m = fmaxf(Af * ev[e], Bf * fv[e]);
                wv[e] = (mbyte & (1u << e)) ? m : 0.f;
            }
            denom += ((wv[0] + wv[1]) + (wv[2] + wv[3])) +
                     ((wv[4] + wv[5]) + (wv[6] + wv[7]));
            f16x8 pa = {(f16)wv[0], (f16)wv[1], (f16)wv[2], (f16)wv[3],
                        (f16)wv[4], (f16)wv[5], (f16)wv[6], (f16)wv[7]};
#pragma unroll
            for (int dh = 0; dh < 2; ++dh) {
                const int d = dh * 32 + r32;
                f16x8 v8 = *(const f16x8*)(lb + d * 128 +
                               ((((jts << 1) | hi) ^ gsz(d)) << 4));
                acc[dh] = __builtin_amdgcn_mfma_f32_32x32x16_f16(
                    pa, v8, acc[dh], 0, 0, 0);
            }
        }
    }
#undef STAGE8

    // row denom: lanes l and l^32 hold the two j-halves of row (l&31)
    denom += __shfl_xor(denom, 32);

    __syncthreads();                 // all compute done; stage area reusable
    float* stash = (float*)pool;     // chunks 1..3: [cw][dh][lane][16f32]
    if (c != 0) {
        float* sb = stash + ((c - 1) * 4 + rw) * 2048 + l * 16;
#pragma unroll
        for (int dh = 0; dh < 2; ++dh)
#pragma unroll
            for (int sub = 0; sub < 4; ++sub) {
                f32x4 v = {acc[dh][sub * 4], acc[dh][sub * 4 + 1],
                           acc[dh][sub * 4 + 2], acc[dh][sub * 4 + 3]};
                *(f32x4*)&sb[dh * 1024 + ((sub ^ (l & 3)) << 2)] = v;
            }
    }
    if (l < 32) dden[c * 128 + rw * 32 + l] = denom;
    __syncthreads();

    if (c == 0) {
#pragma unroll
        for (int cc = 0; cc < 3; ++cc) {
            const float* sr = stash + (cc * 4 + rw) * 2048 + l * 16;
#pragma unroll
            for (int dh = 0; dh < 2; ++dh)
#pragma unroll
                for (int sub = 0; sub < 4; ++sub) {
                    f32x4 v = *(const f32x4*)&sr[dh * 1024 + ((sub ^ (l & 3)) << 2)];
#pragma unroll
                    for (int m = 0; m < 4; ++m) acc[dh][sub * 4 + m] += v[m];
                }
        }
        float* op = out + ((size_t)(b * NN) + i0 + rw * 32) * (NK * ND) + k * ND;
#pragma unroll
        for (int g4 = 0; g4 < 4; ++g4) {
            f32x4 ds = {0.f, 0.f, 0.f, 0.f};
#pragma unroll
            for (int c4 = 0; c4 < 4; ++c4) {
                f32x4 dv = *(const f32x4*)&dden[c4 * 128 + rw * 32 + g4 * 8 + hi * 4];
#pragma unroll
                for (int m = 0; m < 4; ++m) ds[m] += dv[m];
            }
#pragma unroll
            for (int m = 0; m < 4; ++m) {
                const int rr   = g4 * 4 + m;
                const int irow = g4 * 8 + hi * 4 + m;   // C/D row map (m74/m101)
                const float inv = 1.f / (ds[m] + 1e-10f);
                op[(size_t)irow * (NK * ND) + r32]      = acc[0][rr] * inv;
                op[(size_t)irow * (NK * ND) + 32 + r32] = acc[1][rr] * inv;
            }
        }
    }
}

extern "C" void kernel_launch(void* const* d_in, const int* in_sizes, int n_in,
                              void* d_out, int out_size, void* d_ws, size_t ws_size,
                              hipStream_t stream) {
    const float* x     = (const float*)d_in[0];
    const int*   adj   = (const int*)d_in[1];
    const float* Wm    = (const float*)d_in[2];
    const float* a_src = (const float*)d_in[3];
    const float* a_dst = (const float*)d_in[4];
    float* out = (float*)d_out;

    char* ws = (char*)d_ws;
    f16*   wht  = (f16*)ws;                                   // 4 MiB
    float* sbuf = (float*)(ws + (4u << 20));                  // 128 KiB
    float* ebuf = (float*)(ws + (4u << 20) + (128u << 10));   // 128 KiB
    float* fbuf = (float*)(ws + (4u << 20) + (256u << 10));   // 128 KiB
    unsigned int* abit = (unsigned int*)(ws + (4u << 20) + (384u << 10)); // 2 MiB

    k01<<<dim3(256 + NB * NN / 4), 256, 0, stream>>>(
        x, adj, Wm, a_src, a_dst, abit, wht, sbuf, ebuf, fbuf);
    k2_attn<<<dim3(NN / 128, NK, NB), 1024, 0, stream>>>(
        abit, wht, sbuf, ebuf, fbuf, out);
}

// Round 8
// 42.715 us; speedup vs baseline: 3.9361x; 1.0858x over previous
//
#include <hip/hip_runtime.h>

#define NB 4
#define NN 2048
#define NF 256
#define NK 4
#define ND 64
#define NEG 0.2f
#define LOG2E 1.4426950408889634f

typedef _Float16 f16;
typedef _Float16 f16x2 __attribute__((ext_vector_type(2)));
typedef _Float16 f16x4 __attribute__((ext_vector_type(4)));
typedef _Float16 f16x8 __attribute__((ext_vector_type(8)));
typedef float f32x4 __attribute__((ext_vector_type(4)));
typedef float f32x16 __attribute__((ext_vector_type(16)));
typedef unsigned int u32;
typedef unsigned short u16;

// 3-bit group swizzle for the wht slab layout (k1 store must match k2 read)
__device__ __forceinline__ int gsz(int d) { return (d ^ (d >> 3)) & 7; }

// ---------------------------------------------------------------------------
// K01: merged k1 (GEMM, blocks 0..255) + k0 (adj bit-pack, blocks 256..2303).
// k1: Wh^T = (x @ W)^T per (b,k), f16. Global layout: 32 slabs of 8KB per
//   (b,k); slab s covers j in [s*64,s*64+64):
//     elem(d, j) at s*4096 + d*64 + ((g ^ gsz(d))<<3) + (j&7),  g=(j>>3)&7
//   Epilogue: s = Wh a_src -> sbuf(f32); t -> E=exp(t), F=exp(0.2t) as f16.
// k0: abit[b][i][jw] = bits of (adj>0 | I), 64 words/row.
// ---------------------------------------------------------------------------
__global__ __launch_bounds__(256) void k01(
    const float* __restrict__ x,      // (B,N,F)
    const int*   __restrict__ adj,    // (B,N,N)
    const float* __restrict__ Wm,     // (K,F,D)
    const float* __restrict__ a_src,  // (K,D)
    const float* __restrict__ a_dst,  // (K,D)
    unsigned int* __restrict__ abit,  // (B,N,64)
    f16* __restrict__ wht,            // slab layout, see above
    float* __restrict__ sbuf,         // (B,K,N) f32
    f16* __restrict__ ebuf,           // (B,K,N) f16 exp(t)
    f16* __restrict__ fbuf)           // (B,K,N) f16 exp(0.2 t)
{
    __shared__ f16 wt[64 * 256];  // k1 only: W^T, xor-swizzled in f

    const int bx  = blockIdx.x;
    const int tid = threadIdx.x;

    if (bx >= 256) {
        // ---------------- k0: bit-pack ----------------
        const int row = (bx - 256) * 4 + (tid >> 6);  // b*NN + i
        const int l   = tid & 63;
        const int i   = row & (NN - 1);
        const int* __restrict__ ar = adj + (size_t)row * NN;

        int v[32];
#pragma unroll
        for (int c = 0; c < 32; ++c) v[c] = ar[c * 64 + l];

        unsigned int kx = 0, ky = 0;
#pragma unroll
        for (int c = 0; c < 32; ++c) {
            unsigned long long m = __ballot(v[c] > 0);
            if (l == c) { kx = (unsigned int)m; ky = (unsigned int)(m >> 32); }
        }
        if (l == (i >> 6)) {          // self-loop bit
            unsigned int sb = 1u << (i & 31);
            if (((i >> 5) & 1) == 0) kx |= sb; else ky |= sb;
        }
        if (l < 32) {
            uint2 kk; kk.x = kx; kk.y = ky;
            *(uint2*)&abit[(size_t)row * 64 + l * 2] = kk;
        }
        return;
    }

    // ---------------- k1: GEMM ----------------
    const int gx  = bx & 15;      // n-group of 128
    const int k   = (bx >> 4) & 3;
    const int b   = bx >> 6;
    const int wv  = tid >> 6;
    const int l   = tid & 63;
    const int q   = l >> 4;
    const int r16 = l & 15;

    for (int fc = 0; fc < 64; ++fc) {
        int f = fc * 4 + wv;
        int d = l;
        wt[d * 256 + (f ^ ((d & 7) << 3))] = (f16)Wm[(k * NF + f) * ND + d];
    }
    __syncthreads();

    const int ncol0 = gx * 128 + wv * 32;
    f32x4 acc[2][4];
#pragma unroll
    for (int nt = 0; nt < 2; ++nt)
#pragma unroll
        for (int dt = 0; dt < 4; ++dt)
            acc[nt][dt] = (f32x4){0.f, 0.f, 0.f, 0.f};

    for (int fs = 0; fs < 16; ++fs) {           // K-steps of 16
        const int f0 = fs * 16 + q * 4;
        f16x4 af[4];
#pragma unroll
        for (int dt = 0; dt < 4; ++dt) {
            int d = dt * 16 + r16;
            af[dt] = *(const f16x4*)&wt[d * 256 + (f0 ^ ((d & 7) << 3))];
        }
#pragma unroll
        for (int nt = 0; nt < 2; ++nt) {
            int n = ncol0 + nt * 16 + r16;
            float4 xv = *(const float4*)&x[((size_t)(b * NN + n)) * NF + f0];
            f16x4 bf = {(f16)xv.x, (f16)xv.y, (f16)xv.z, (f16)xv.w};
#pragma unroll
            for (int dt = 0; dt < 4; ++dt)
                acc[nt][dt] = __builtin_amdgcn_mfma_f32_16x16x16f16(
                    af[dt], bf, acc[nt][dt], 0, 0, 0);
        }
    }

    float asv[4][4], adv[4][4];
#pragma unroll
    for (int dt = 0; dt < 4; ++dt)
#pragma unroll
        for (int rr = 0; rr < 4; ++rr) {
            int d = dt * 16 + q * 4 + rr;
            asv[dt][rr] = a_src[k * ND + d];
            adv[dt][rr] = a_dst[k * ND + d];
        }

    const size_t obase = (size_t)(b * NK + k) * 131072;

#pragma unroll
    for (int nt = 0; nt < 2; ++nt) {
        int n  = ncol0 + nt * 16 + r16;
        int s_ = n >> 6, g = (n >> 3) & 7, e = n & 7;
        float sp = 0.f, tp = 0.f;
#pragma unroll
        for (int dt = 0; dt < 4; ++dt)
#pragma unroll
            for (int rr = 0; rr < 4; ++rr) {
                float v = acc[nt][dt][rr];
                int d = dt * 16 + q * 4 + rr;    // C row = d'
                wht[obase + s_ * 4096 + d * 64 + ((g ^ gsz(d)) << 3) + e] = (f16)v;
                sp += v * asv[dt][rr];
                tp += v * adv[dt][rr];
            }
        sp += __shfl_xor(sp, 16);
        sp += __shfl_xor(sp, 32);
        tp += __shfl_xor(tp, 16);
        tp += __shfl_xor(tp, 32);
        if (q == 0) {
            int idx = (b * NK + k) * NN + n;
            sbuf[idx] = sp;
            ebuf[idx] = (f16)__builtin_exp2f(tp * LOG2E);
            fbuf[idx] = (f16)__builtin_exp2f(0.2f * LOG2E * tp);
        }
    }
}

// ---------------------------------------------------------------------------
// K2 v8: packed-f16 scoring + 2 blocks/CU.
// Block = 512 thr = 8 waves = 2 row-waves (64 i) x 4 j-chunks (512 j).
// Grid 512 = 2 blocks/CU (LDS 73KB). Per iter (64 j): 8KB slab staged by the
// chunk's 2 waves (2-buf, counted vmcnt, one raw s_barrier/iter).
// Score per f16-PAIR: w2 = pk_max(Af2*E2, Bf2*F2); mask = AND with FFFF/0000
// halfwords from ((byte*0x8001)>>2p & 0x00010001)*0xFFFF; denom via fdot2 on
// the masked pa (numerator == denominator weights bit-exactly).
// ---------------------------------------------------------------------------
__global__ __launch_bounds__(512, 4) void k2_attn(
    const unsigned int* __restrict__ abit,  // (B,N,64) bit-mask
    const f16* __restrict__ wht,            // slab layout
    const float* __restrict__ sbuf,         // (B,K,N)
    const f16* __restrict__ ebuf,           // (B,K,N) f16
    const f16* __restrict__ fbuf,           // (B,K,N) f16
    float* __restrict__ out)                // (B,N,K*D)
{
    const int i0  = blockIdx.x * 64;
    const int k   = blockIdx.y;
    const int b   = blockIdx.z;
    const int tid = threadIdx.x;
    const int w   = tid >> 6;
    const int c   = w >> 1;          // j-chunk 0..3
    const int rw  = w & 1;           // row-wave 0..1
    const int l   = tid & 63;
    const int r32 = l & 31;
    const int hi  = l >> 5;
    const int iglob = i0 + rw * 32 + r32;

    // LDS: [0,64K) stage (chunk c at c*16K, 2 bufs of 8K; reused as stash);
    // [64K,68K) el f16; [68K,72K) fl f16; [72K,+1K) dden
    __shared__ __attribute__((aligned(16))) char pool[74752];
    u16*   el   = (u16*)(pool + 65536);
    u16*   fl   = (u16*)(pool + 69632);
    float* dden = (float*)(pool + 73728);

    // adj bits: 8 iters x 64 bits for this lane's row, this chunk
    const unsigned int* __restrict__ abrow =
        abit + (size_t)(b * NN + iglob) * 64 + c * 16;
    uint2 abx[8];
#pragma unroll
    for (int it = 0; it < 8; ++it) abx[it] = *(const uint2*)(abrow + it * 2);

    {   // stage E/F as f16 (4KB each), coalesced, once
        const u16* eb = (const u16*)(ebuf + (b * NK + k) * NN);
        const u16* fb = (const u16*)(fbuf + (b * NK + k) * NN);
        *(ushort4*)&el[tid * 4] = *(const ushort4*)&eb[tid * 4];
        *(ushort4*)&fl[tid * 4] = *(const ushort4*)&fb[tid * 4];
    }

    const float s   = sbuf[(b * NK + k) * NN + iglob];
    const float Aff = __builtin_exp2f(0.8f * LOG2E * fminf(s, 0.f));   // <= 1
    const float Bff = __builtin_exp2f(-0.8f * LOG2E * fmaxf(s, 0.f));  // <= 1
    const f16 Afh = (f16)Aff, Bfh = (f16)Bff;
    const f16x2 Af2 = {Afh, Afh};
    const f16x2 Bf2 = {Bfh, Bfh};
    const f16x2 one2 = {(f16)1.0f, (f16)1.0f};
    const char* gtiles = (const char*)wht + (size_t)(b * NK + k) * 262144;

    float denom = 0.f;
    f32x16 acc[2];
#pragma unroll
    for (int dh = 0; dh < 2; ++dh)
#pragma unroll
        for (int z = 0; z < 16; ++z) acc[dh][z] = 0.f;

#define STAGE8(bb, it)                                                         \
    do {                                                                       \
        const char* gsrc = gtiles + (size_t)(c * 8 + (it)) * 8192 +            \
                           rw * 1024 + l * 16;                                 \
        char* ldst = pool + c * 16384 + (bb) * 8192 + rw * 1024 + l * 16;      \
        _Pragma("unroll") for (int kk = 0; kk < 4; ++kk)                       \
            __builtin_amdgcn_global_load_lds(                                  \
                (const __attribute__((address_space(1))) void*)(gsrc +         \
                    kk * 2048),                                                \
                (__attribute__((address_space(3))) void*)(ldst + kk * 2048),   \
                16, 0, 0);                                                     \
    } while (0)

    STAGE8(0, 0);

#pragma unroll
    for (int it = 0; it < 8; ++it) {
        // drain stage(it) (and, at it=0, all prologue loads + E/F ds_writes)
        asm volatile("s_waitcnt vmcnt(0) lgkmcnt(0)" ::: "memory");
        __builtin_amdgcn_sched_barrier(0);
        __builtin_amdgcn_s_barrier();
        __builtin_amdgcn_sched_barrier(0);
        if (it < 7) STAGE8((it + 1) & 1, it + 1);  // buf freed by compute(it-1)

        const char* lb = pool + c * 16384 + (it & 1) * 8192;
        const uint2 ab = abx[it];
#pragma unroll
        for (int jts = 0; jts < 4; ++jts) {
            const u32 word = (jts & 2) ? ab.y : ab.x;
            const u32 bbyte = (word >> (((jts & 1) << 4) + (hi << 3))) & 0xffu;
            const u32 u = bbyte * 0x8001u;         // byte | byte<<15
            const int jb = c * 512 + it * 64 + jts * 16 + hi * 8;
            uint4 E4 = *(const uint4*)&el[jb];
            uint4 F4 = *(const uint4*)&fl[jb];
            u32 pa_u[4];
#pragma unroll
            for (int p = 0; p < 4; ++p) {
                f16x2 e2 = __builtin_bit_cast(f16x2, ((const u32*)&E4)[p]);
                f16x2 f2 = __builtin_bit_cast(f16x2, ((const u32*)&F4)[p]);
                f16x2 w2 = __builtin_elementwise_max(Af2 * e2, Bf2 * f2);
                u32 x  = (u >> (2 * p)) & 0x00010001u;   // {bit2p+1, bit2p}
                u32 mm = x * 0xffffu;                    // FFFF/0000 halves
                u32 wu = __builtin_bit_cast(u32, w2) & mm;
                pa_u[p] = wu;
                denom = __builtin_amdgcn_fdot2(
                    __builtin_bit_cast(f16x2, wu), one2, denom, false);
            }
            uint4 pav = {pa_u[0], pa_u[1], pa_u[2], pa_u[3]};
            f16x8 pa = __builtin_bit_cast(f16x8, pav);
#pragma unroll
            for (int dh = 0; dh < 2; ++dh) {
                const int d = dh * 32 + r32;
                f16x8 v8 = *(const f16x8*)(lb + d * 128 +
                               ((((jts << 1) | hi) ^ gsz(d)) << 4));
                acc[dh] = __builtin_amdgcn_mfma_f32_32x32x16_f16(
                    pa, v8, acc[dh], 0, 0, 0);
            }
        }
    }
#undef STAGE8

    // row denom: lanes l and l^32 hold the two j-halves of row (l&31)
    denom += __shfl_xor(denom, 32);

    __syncthreads();                 // all compute done; stage area reusable
    float* stash = (float*)pool;     // chunks 1..3: [(c-1)*2+rw][lane][32f32]
    if (c != 0) {
        float* sb = stash + ((c - 1) * 2 + rw) * 2048 + l * 32;
#pragma unroll
        for (int dh = 0; dh < 2; ++dh)
#pragma unroll
            for (int sub = 0; sub < 4; ++sub) {
                f32x4 v = {acc[dh][sub * 4], acc[dh][sub * 4 + 1],
                           acc[dh][sub * 4 + 2], acc[dh][sub * 4 + 3]};
                *(f32x4*)&sb[dh * 16 + ((sub ^ (l & 3)) << 2)] = v;
            }
    }
    if (hi == 0) dden[c * 64 + rw * 32 + r32] = denom;
    __syncthreads();

    if (c == 0) {
#pragma unroll
        for (int cc = 0; cc < 3; ++cc) {
            const float* sr = stash + (cc * 2 + rw) * 2048 + l * 32;
#pragma unroll
            for (int dh = 0; dh < 2; ++dh)
#pragma unroll
                for (int sub = 0; sub < 4; ++sub) {
                    f32x4 v = *(const f32x4*)&sr[dh * 16 + ((sub ^ (l & 3)) << 2)];
#pragma unroll
                    for (int m = 0; m < 4; ++m) acc[dh][sub * 4 + m] += v[m];
                }
        }
        float* op = out + ((size_t)(b * NN) + i0 + rw * 32) * (NK * ND) + k * ND;
#pragma unroll
        for (int g4 = 0; g4 < 4; ++g4) {
            f32x4 ds = {0.f, 0.f, 0.f, 0.f};
#pragma unroll
            for (int c4 = 0; c4 < 4; ++c4) {
                f32x4 dv = *(const f32x4*)&dden[c4 * 64 + rw * 32 + g4 * 8 + hi * 4];
#pragma unroll
                for (int m = 0; m < 4; ++m) ds[m] += dv[m];
            }
#pragma unroll
            for (int m = 0; m < 4; ++m) {
                const int rr   = g4 * 4 + m;
                const int irow = g4 * 8 + hi * 4 + m;   // C/D row map (m74/m101)
                const float inv = 1.f / (ds[m] + 1e-10f);
                op[(size_t)irow * (NK * ND) + r32]      = acc[0][rr] * inv;
                op[(size_t)irow * (NK * ND) + 32 + r32] = acc[1][rr] * inv;
            }
        }
    }
}

extern "C" void kernel_launch(void* const* d_in, const int* in_sizes, int n_in,
                              void* d_out, int out_size, void* d_ws, size_t ws_size,
                              hipStream_t stream) {
    const float* x     = (const float*)d_in[0];
    const int*   adj   = (const int*)d_in[1];
    const float* Wm    = (const float*)d_in[2];
    const float* a_src = (const float*)d_in[3];
    const float* a_dst = (const float*)d_in[4];
    float* out = (float*)d_out;

    char* ws = (char*)d_ws;
    f16*   wht  = (f16*)ws;                                   // 4 MiB
    float* sbuf = (float*)(ws + (4u << 20));                  // 128 KiB
    f16*   ebuf = (f16*)(ws + (4u << 20) + (128u << 10));     // 64 KiB
    f16*   fbuf = (f16*)(ws + (4u << 20) + (192u << 10));     // 64 KiB
    unsigned int* abit = (unsigned int*)(ws + (4u << 20) + (256u << 10)); // 2 MiB

    k01<<<dim3(256 + NB * NN / 4), 256, 0, stream>>>(
        x, adj, Wm, a_src, a_dst, abit, wht, sbuf, ebuf, fbuf);
    k2_attn<<<dim3(NN / 64, NK, NB), 512, 0, stream>>>(
        abit, wht, sbuf, ebuf, fbuf, out);
}